// Round 1
// baseline (904.428 us; speedup 1.0000x reference)
//
#include <hip/hip_runtime.h>

#define N_NODES 100000
#define EMB_DIM 64
#define N_EDGES 1200000
#define N_LAYERS 3

// ---------------------------------------------------------------------------
// deg[col[e]] += ew[e]
__global__ void deg_kernel(const float* __restrict__ ew,
                           const int* __restrict__ col,
                           float* __restrict__ deg) {
    int e = blockIdx.x * blockDim.x + threadIdx.x;
    if (e < N_EDGES) {
        atomicAdd(&deg[col[e]], ew[e]);
    }
}

// deg -> dinv in place
__global__ void dinv_kernel(float* __restrict__ deg) {
    int n = blockIdx.x * blockDim.x + threadIdx.x;
    if (n < N_NODES) {
        float d = deg[n];
        deg[n] = (d > 0.0f) ? rsqrtf(d) : 0.0f;
    }
}

// norm[e] = dinv[row[e]] * ew[e] * dinv[col[e]]
__global__ void norm_kernel(const float* __restrict__ ew,
                            const int* __restrict__ row,
                            const int* __restrict__ col,
                            const float* __restrict__ dinv,
                            float* __restrict__ nrm) {
    int e = blockIdx.x * blockDim.x + threadIdx.x;
    if (e < N_EDGES) {
        nrm[e] = dinv[row[e]] * ew[e] * dinv[col[e]];
    }
}

// xout[col[e]][d] += norm[e] * xin[row[e]][d]
// thread t: e = t>>6, d = t&63  (64 lanes = one edge -> coalesced row access)
__global__ void prop_kernel(const float* __restrict__ xin,
                            float* __restrict__ xout,
                            const int* __restrict__ row,
                            const int* __restrict__ col,
                            const float* __restrict__ nrm) {
    int t = blockIdx.x * blockDim.x + threadIdx.x;
    int e = t >> 6;
    int d = t & 63;
    if (e < N_EDGES) {
        int r = row[e];
        int c = col[e];
        float v = nrm[e] * xin[r * EMB_DIM + d];
        atomicAdd(&xout[c * EMB_DIM + d], v);
    }
}

// comb = sum_l softmax(lw)[l] * x_l ; out = comb / max(||comb||_2, 1e-12)
// one wave (64 lanes) per node row
__global__ void combine_kernel(const float* __restrict__ x0,
                               const float* __restrict__ x1,
                               const float* __restrict__ x2,
                               const float* __restrict__ x3,
                               const float* __restrict__ lw,
                               float* __restrict__ out) {
    int t = blockIdx.x * blockDim.x + threadIdx.x;
    int n = t >> 6;
    if (n >= N_NODES) return;

    float w0 = lw[0], w1 = lw[1], w2 = lw[2], w3 = lw[3];
    float m = fmaxf(fmaxf(w0, w1), fmaxf(w2, w3));
    float e0 = expf(w0 - m), e1 = expf(w1 - m), e2 = expf(w2 - m), e3 = expf(w3 - m);
    float inv_s = 1.0f / (e0 + e1 + e2 + e3);

    float v = (e0 * x0[t] + e1 * x1[t] + e2 * x2[t] + e3 * x3[t]) * inv_s;

    // row L2 norm across the 64 lanes of this wave
    float sq = v * v;
    #pragma unroll
    for (int o = 32; o > 0; o >>= 1) {
        sq += __shfl_xor(sq, o, 64);
    }
    float nrm = fmaxf(sqrtf(sq), 1e-12f);
    out[t] = v / nrm;
}

// ---------------------------------------------------------------------------
extern "C" void kernel_launch(void* const* d_in, const int* in_sizes, int n_in,
                              void* d_out, int out_size, void* d_ws, size_t ws_size,
                              hipStream_t stream) {
    const float* emb = (const float*)d_in[0];   // [N, 64]
    const float* lw  = (const float*)d_in[1];   // [4]
    const float* ew  = (const float*)d_in[2];   // [E]
    const int*   ei  = (const int*)d_in[3];     // [2, E] (int32 on device)
    const int* row = ei;                        // sources
    const int* col = ei + N_EDGES;              // targets
    float* out = (float*)d_out;

    // workspace layout
    float* deg = (float*)d_ws;                                   // N (becomes dinv)
    float* nrm = deg + ((N_NODES + 127) & ~127);                 // E
    float* x1  = nrm + ((N_EDGES + 127) & ~127);                 // N*64
    float* x2  = x1 + (size_t)N_NODES * EMB_DIM;                 // N*64
    float* x3  = x2 + (size_t)N_NODES * EMB_DIM;                 // N*64

    // zero accumulators
    hipMemsetAsync(deg, 0, N_NODES * sizeof(float), stream);
    hipMemsetAsync(x1, 0, (size_t)N_NODES * EMB_DIM * 3 * sizeof(float), stream);

    const int B = 256;
    deg_kernel<<<(N_EDGES + B - 1) / B, B, 0, stream>>>(ew, col, deg);
    dinv_kernel<<<(N_NODES + B - 1) / B, B, 0, stream>>>(deg);
    norm_kernel<<<(N_EDGES + B - 1) / B, B, 0, stream>>>(ew, row, col, deg, nrm);

    long prop_threads = (long)N_EDGES * EMB_DIM;  // 76.8M
    int prop_blocks = (int)((prop_threads + B - 1) / B);
    prop_kernel<<<prop_blocks, B, 0, stream>>>(emb, x1, row, col, nrm);
    prop_kernel<<<prop_blocks, B, 0, stream>>>(x1, x2, row, col, nrm);
    prop_kernel<<<prop_blocks, B, 0, stream>>>(x2, x3, row, col, nrm);

    long comb_threads = (long)N_NODES * EMB_DIM;  // 6.4M
    combine_kernel<<<(int)((comb_threads + B - 1) / B), B, 0, stream>>>(
        emb, x1, x2, x3, lw, out);
}

// Round 2
// 547.297 us; speedup vs baseline: 1.6525x; 1.6525x over previous
//
#include <hip/hip_runtime.h>

#define N_NODES 100000
#define EMB_DIM 64
#define N_EDGES 1200000
#define N_LAYERS 3

struct __align__(8) EdgeRec {
    int   s;   // source node
    float w;   // dinv[src] * edge_weight
};

// ---------------------------------------------------------------------------
// count[col]++ (int) and deg[col] += ew (float), one pass over edges
__global__ void hist_kernel(const float* __restrict__ ew,
                            const int* __restrict__ col,
                            int* __restrict__ count,
                            float* __restrict__ deg) {
    int e = blockIdx.x * blockDim.x + threadIdx.x;
    if (e < N_EDGES) {
        int c = col[e];
        atomicAdd(&count[c], 1);
        atomicAdd(&deg[c], ew[e]);
    }
}

// deg -> dinv in place
__global__ void dinv_kernel(float* __restrict__ deg) {
    int n = blockIdx.x * blockDim.x + threadIdx.x;
    if (n < N_NODES) {
        float d = deg[n];
        deg[n] = (d > 0.0f) ? rsqrtf(d) : 0.0f;
    }
}

// exclusive prefix scan of count[N] -> start[N+1], single block of 1024 threads
__global__ void scan_kernel(const int* __restrict__ cnt, int* __restrict__ start) {
    const int K = (N_NODES + 1023) / 1024;  // 98
    int tid  = threadIdx.x;
    int lane = tid & 63;
    int wid  = tid >> 6;
    int base = tid * K;

    // pass 1: per-thread sum
    int sum = 0;
    for (int i = 0; i < K; ++i) {
        int idx = base + i;
        if (idx < N_NODES) sum += cnt[idx];
    }

    // inclusive scan of 'sum' within wave
    int v = sum;
    #pragma unroll
    for (int off = 1; off < 64; off <<= 1) {
        int u = __shfl_up(v, off, 64);
        if (lane >= off) v += u;
    }

    __shared__ int wsum[16];
    if (lane == 63) wsum[wid] = v;
    __syncthreads();

    int woff = 0;
    for (int w = 0; w < wid; ++w) woff += wsum[w];

    int excl = woff + v - sum;  // exclusive prefix across all threads

    // pass 2: write running offsets
    int run = excl;
    for (int i = 0; i < K; ++i) {
        int idx = base + i;
        if (idx < N_NODES) {
            start[idx] = run;
            run += cnt[idx];
        }
    }
    if (tid == 1023) start[N_NODES] = woff + v;  // total == N_EDGES
}

// scatter edges into CSR order: rec[start[c] + cursor[c]++] = {row, dinv[row]*ew}
__global__ void scatter_kernel(const int* __restrict__ row,
                               const int* __restrict__ col,
                               const float* __restrict__ ew,
                               const float* __restrict__ dinv,
                               const int* __restrict__ start,
                               int* __restrict__ cursor,
                               EdgeRec* __restrict__ rec) {
    int e = blockIdx.x * blockDim.x + threadIdx.x;
    if (e < N_EDGES) {
        int c = col[e];
        int r = row[e];
        int pos = start[c] + atomicAdd(&cursor[c], 1);
        EdgeRec rc;
        rc.s = r;
        rc.w = dinv[r] * ew[e];
        rec[pos] = rc;
    }
}

// xout[n][d] = dinv[n] * sum_j w_j * xin[src_j][d]; one wave per node
__global__ void prop_kernel(const float* __restrict__ xin,
                            float* __restrict__ xout,
                            const EdgeRec* __restrict__ rec,
                            const int* __restrict__ start,
                            const float* __restrict__ dinv) {
    int t = blockIdx.x * blockDim.x + threadIdx.x;
    int n = t >> 6;
    int d = t & 63;
    if (n >= N_NODES) return;

    int s = start[n], e = start[n + 1];
    float acc = 0.0f;
    int j = s;
    for (; j + 4 <= e; j += 4) {
        EdgeRec r0 = rec[j], r1 = rec[j + 1], r2 = rec[j + 2], r3 = rec[j + 3];
        float v0 = xin[r0.s * EMB_DIM + d];
        float v1 = xin[r1.s * EMB_DIM + d];
        float v2 = xin[r2.s * EMB_DIM + d];
        float v3 = xin[r3.s * EMB_DIM + d];
        acc += r0.w * v0;
        acc += r1.w * v1;
        acc += r2.w * v2;
        acc += r3.w * v3;
    }
    for (; j < e; ++j) {
        EdgeRec r = rec[j];
        acc += r.w * xin[r.s * EMB_DIM + d];
    }
    xout[t] = dinv[n] * acc;
}

// last propagation fused with weighted layer-combine + row L2-normalize
__global__ void prop_combine_kernel(const float* __restrict__ x2,     // input to layer 3
                                    const float* __restrict__ x0,     // emb
                                    const float* __restrict__ x1,
                                    const EdgeRec* __restrict__ rec,
                                    const int* __restrict__ start,
                                    const float* __restrict__ dinv,
                                    const float* __restrict__ lw,
                                    float* __restrict__ out) {
    int t = blockIdx.x * blockDim.x + threadIdx.x;
    int n = t >> 6;
    int d = t & 63;
    if (n >= N_NODES) return;

    int s = start[n], e = start[n + 1];
    float acc = 0.0f;
    int j = s;
    for (; j + 4 <= e; j += 4) {
        EdgeRec r0 = rec[j], r1 = rec[j + 1], r2 = rec[j + 2], r3 = rec[j + 3];
        float v0 = x2[r0.s * EMB_DIM + d];
        float v1 = x2[r1.s * EMB_DIM + d];
        float v2 = x2[r2.s * EMB_DIM + d];
        float v3 = x2[r3.s * EMB_DIM + d];
        acc += r0.w * v0;
        acc += r1.w * v1;
        acc += r2.w * v2;
        acc += r3.w * v3;
    }
    for (; j < e; ++j) {
        EdgeRec r = rec[j];
        acc += r.w * x2[r.s * EMB_DIM + d];
    }
    float x3v = dinv[n] * acc;

    // softmax over 4 layer weights (tiny, per-thread)
    float w0 = lw[0], w1 = lw[1], w2 = lw[2], w3 = lw[3];
    float m = fmaxf(fmaxf(w0, w1), fmaxf(w2, w3));
    float e0 = expf(w0 - m), e1 = expf(w1 - m), e2 = expf(w2 - m), e3 = expf(w3 - m);
    float inv_s = 1.0f / (e0 + e1 + e2 + e3);

    float v = (e0 * x0[t] + e1 * x1[t] + e2 * x2[t] + e3 * x3v) * inv_s;

    float sq = v * v;
    #pragma unroll
    for (int o = 32; o > 0; o >>= 1) sq += __shfl_xor(sq, o, 64);
    float nrm = fmaxf(sqrtf(sq), 1e-12f);
    out[t] = v / nrm;
}

// ---------------------------------------------------------------------------
extern "C" void kernel_launch(void* const* d_in, const int* in_sizes, int n_in,
                              void* d_out, int out_size, void* d_ws, size_t ws_size,
                              hipStream_t stream) {
    const float* emb = (const float*)d_in[0];   // [N, 64]
    const float* lw  = (const float*)d_in[1];   // [4]
    const float* ew  = (const float*)d_in[2];   // [E]
    const int*   ei  = (const int*)d_in[3];     // [2, E]
    const int* row = ei;                        // sources
    const int* col = ei + N_EDGES;              // targets
    float* out = (float*)d_out;

    // workspace layout (8B alignment for rec at base)
    char* p = (char*)d_ws;
    EdgeRec* rec = (EdgeRec*)p;                 p += (size_t)N_EDGES * sizeof(EdgeRec); // 9.6 MB
    float* x1    = (float*)p;                   p += (size_t)N_NODES * EMB_DIM * 4;     // 25.6 MB
    float* x2    = (float*)p;                   p += (size_t)N_NODES * EMB_DIM * 4;     // 25.6 MB
    float* dinv  = (float*)p;                   p += (size_t)N_NODES * 4;
    int*   count = (int*)p;                     p += (size_t)N_NODES * 4;
    int*   cursor= (int*)p;                     p += (size_t)N_NODES * 4;
    int*   startA= (int*)p;                     p += (size_t)(N_NODES + 1) * 4;

    hipMemsetAsync(dinv,   0, N_NODES * sizeof(float), stream);
    hipMemsetAsync(count,  0, N_NODES * sizeof(int),   stream);
    hipMemsetAsync(cursor, 0, N_NODES * sizeof(int),   stream);

    const int B = 256;
    int egrid = (N_EDGES + B - 1) / B;
    int ngrid = (N_NODES + B - 1) / B;

    hist_kernel<<<egrid, B, 0, stream>>>(ew, col, count, dinv);
    dinv_kernel<<<ngrid, B, 0, stream>>>(dinv);
    scan_kernel<<<1, 1024, 0, stream>>>(count, startA);
    scatter_kernel<<<egrid, B, 0, stream>>>(row, col, ew, dinv, startA, cursor, rec);

    long rt = (long)N_NODES * EMB_DIM;  // 6.4M threads, one wave per node
    int rgrid = (int)((rt + B - 1) / B);
    prop_kernel<<<rgrid, B, 0, stream>>>(emb, x1, rec, startA, dinv);
    prop_kernel<<<rgrid, B, 0, stream>>>(x1, x2, rec, startA, dinv);
    prop_combine_kernel<<<rgrid, B, 0, stream>>>(x2, emb, x1, rec, startA, dinv, lw, out);
}

// Round 3
// 379.279 us; speedup vs baseline: 2.3846x; 1.4430x over previous
//
#include <hip/hip_runtime.h>

#define N_NODES 100000
#define EMB_DIM 64
#define N_EDGES 1200000
#define N_LAYERS 3

#define SCAN_CHUNK 2048
#define SCAN_NBLK  ((N_NODES + SCAN_CHUNK - 1) / SCAN_CHUNK)   // 49

struct __align__(8) EdgeRec {
    int   s;   // source node
    float w;   // dinv[src] * edge_weight
};

// ---------------------------------------------------------------------------
// count[col]++ (int) and deg[col] += ew (float), one pass over edges
__global__ void hist_kernel(const float* __restrict__ ew,
                            const int* __restrict__ col,
                            int* __restrict__ count,
                            float* __restrict__ deg) {
    int e = blockIdx.x * blockDim.x + threadIdx.x;
    if (e < N_EDGES) {
        int c = col[e];
        atomicAdd(&count[c], 1);
        atomicAdd(&deg[c], ew[e]);
    }
}

// deg -> dinv in place
__global__ void dinv_kernel(float* __restrict__ deg) {
    int n = blockIdx.x * blockDim.x + threadIdx.x;
    if (n < N_NODES) {
        float d = deg[n];
        deg[n] = (d > 0.0f) ? rsqrtf(d) : 0.0f;
    }
}

// ---- hierarchical scan --------------------------------------------------
// pass A: per-block sums of 2048-element chunks (coalesced)
__global__ void scan_partial(const int* __restrict__ cnt, int* __restrict__ bsum) {
    __shared__ int ws[4];
    int b = blockIdx.x;
    int base = b * SCAN_CHUNK;
    int tid = threadIdx.x;
    int sum = 0;
    for (int i = tid; i < SCAN_CHUNK; i += 256) {
        int idx = base + i;
        if (idx < N_NODES) sum += cnt[idx];
    }
    #pragma unroll
    for (int o = 32; o > 0; o >>= 1) sum += __shfl_xor(sum, o, 64);
    if ((tid & 63) == 0) ws[tid >> 6] = sum;
    __syncthreads();
    if (tid == 0) bsum[b] = ws[0] + ws[1] + ws[2] + ws[3];
}

// pass B: one wave exclusive-scans the 49 block sums; writes total to start[N]
__global__ void scan_bsum(const int* __restrict__ bsum,
                          int* __restrict__ boff,
                          int* __restrict__ start) {
    int tid = threadIdx.x;  // 64 threads
    int s = (tid < SCAN_NBLK) ? bsum[tid] : 0;
    int v = s;
    #pragma unroll
    for (int o = 1; o < 64; o <<= 1) {
        int u = __shfl_up(v, o, 64);
        if (tid >= o) v += u;
    }
    if (tid < SCAN_NBLK) boff[tid] = v - s;   // exclusive
    if (tid == 63) start[N_NODES] = v;        // total == N_EDGES
}

// pass C: block-wide exclusive scan of each chunk + block offset
__global__ void scan_final(const int* __restrict__ cnt,
                           const int* __restrict__ boff,
                           int* __restrict__ start) {
    __shared__ int ws[4];
    int b = blockIdx.x;
    int base = b * SCAN_CHUNK;
    int tid = threadIdx.x;
    int lane = tid & 63, wid = tid >> 6;

    // 8 consecutive counts per thread (two int4 loads, coalesced 32B/lane)
    int idx0 = base + tid * 8;
    int loc[8];
    int s = 0;
    if (idx0 + 8 <= N_NODES) {
        int4 a = *(const int4*)(cnt + idx0);
        int4 c = *(const int4*)(cnt + idx0 + 4);
        loc[0] = a.x; loc[1] = a.y; loc[2] = a.z; loc[3] = a.w;
        loc[4] = c.x; loc[5] = c.y; loc[6] = c.z; loc[7] = c.w;
        s = a.x + a.y + a.z + a.w + c.x + c.y + c.z + c.w;
    } else {
        #pragma unroll
        for (int i = 0; i < 8; ++i) {
            int idx = idx0 + i;
            loc[i] = (idx < N_NODES) ? cnt[idx] : 0;
            s += loc[i];
        }
    }

    // exclusive scan of s across 256 threads
    int v = s;
    #pragma unroll
    for (int o = 1; o < 64; o <<= 1) {
        int u = __shfl_up(v, o, 64);
        if (lane >= o) v += u;
    }
    if (lane == 63) ws[wid] = v;
    __syncthreads();
    int woff = 0;
    for (int w = 0; w < wid; ++w) woff += ws[w];

    int run = boff[b] + woff + v - s;
    #pragma unroll
    for (int i = 0; i < 8; ++i) {
        int idx = idx0 + i;
        if (idx < N_NODES) start[idx] = run;
        run += loc[i];
    }
}

// scatter edges into CSR order: rec[start[c] + cursor[c]++] = {row, dinv[row]*ew}
__global__ void scatter_kernel(const int* __restrict__ row,
                               const int* __restrict__ col,
                               const float* __restrict__ ew,
                               const float* __restrict__ dinv,
                               const int* __restrict__ start,
                               int* __restrict__ cursor,
                               EdgeRec* __restrict__ rec) {
    int e = blockIdx.x * blockDim.x + threadIdx.x;
    if (e < N_EDGES) {
        int c = col[e];
        int r = row[e];
        int pos = start[c] + atomicAdd(&cursor[c], 1);
        EdgeRec rc;
        rc.s = r;
        rc.w = dinv[r] * ew[e];
        rec[pos] = rc;
    }
}

// xout[n][d] = dinv[n] * sum_j w_j * xin[src_j][d]; one wave per node
__global__ void prop_kernel(const float* __restrict__ xin,
                            float* __restrict__ xout,
                            const EdgeRec* __restrict__ rec,
                            const int* __restrict__ start,
                            const float* __restrict__ dinv) {
    int t = blockIdx.x * blockDim.x + threadIdx.x;
    int n = t >> 6;
    int d = t & 63;
    if (n >= N_NODES) return;

    int s = start[n], e = start[n + 1];
    float acc = 0.0f;
    int j = s;
    for (; j + 4 <= e; j += 4) {
        EdgeRec r0 = rec[j], r1 = rec[j + 1], r2 = rec[j + 2], r3 = rec[j + 3];
        float v0 = xin[r0.s * EMB_DIM + d];
        float v1 = xin[r1.s * EMB_DIM + d];
        float v2 = xin[r2.s * EMB_DIM + d];
        float v3 = xin[r3.s * EMB_DIM + d];
        acc += r0.w * v0;
        acc += r1.w * v1;
        acc += r2.w * v2;
        acc += r3.w * v3;
    }
    for (; j < e; ++j) {
        EdgeRec r = rec[j];
        acc += r.w * xin[r.s * EMB_DIM + d];
    }
    xout[t] = dinv[n] * acc;
}

// last propagation fused with weighted layer-combine + row L2-normalize
__global__ void prop_combine_kernel(const float* __restrict__ x2,     // input to layer 3
                                    const float* __restrict__ x0,     // emb
                                    const float* __restrict__ x1,
                                    const EdgeRec* __restrict__ rec,
                                    const int* __restrict__ start,
                                    const float* __restrict__ dinv,
                                    const float* __restrict__ lw,
                                    float* __restrict__ out) {
    int t = blockIdx.x * blockDim.x + threadIdx.x;
    int n = t >> 6;
    int d = t & 63;
    if (n >= N_NODES) return;

    int s = start[n], e = start[n + 1];
    float acc = 0.0f;
    int j = s;
    for (; j + 4 <= e; j += 4) {
        EdgeRec r0 = rec[j], r1 = rec[j + 1], r2 = rec[j + 2], r3 = rec[j + 3];
        float v0 = x2[r0.s * EMB_DIM + d];
        float v1 = x2[r1.s * EMB_DIM + d];
        float v2 = x2[r2.s * EMB_DIM + d];
        float v3 = x2[r3.s * EMB_DIM + d];
        acc += r0.w * v0;
        acc += r1.w * v1;
        acc += r2.w * v2;
        acc += r3.w * v3;
    }
    for (; j < e; ++j) {
        EdgeRec r = rec[j];
        acc += r.w * x2[r.s * EMB_DIM + d];
    }
    float x3v = dinv[n] * acc;

    float w0 = lw[0], w1 = lw[1], w2 = lw[2], w3 = lw[3];
    float m = fmaxf(fmaxf(w0, w1), fmaxf(w2, w3));
    float e0 = expf(w0 - m), e1 = expf(w1 - m), e2 = expf(w2 - m), e3 = expf(w3 - m);
    float inv_s = 1.0f / (e0 + e1 + e2 + e3);

    float v = (e0 * x0[t] + e1 * x1[t] + e2 * x2[t] + e3 * x3v) * inv_s;

    float sq = v * v;
    #pragma unroll
    for (int o = 32; o > 0; o >>= 1) sq += __shfl_xor(sq, o, 64);
    float nrm = fmaxf(sqrtf(sq), 1e-12f);
    out[t] = v / nrm;
}

// ---------------------------------------------------------------------------
extern "C" void kernel_launch(void* const* d_in, const int* in_sizes, int n_in,
                              void* d_out, int out_size, void* d_ws, size_t ws_size,
                              hipStream_t stream) {
    const float* emb = (const float*)d_in[0];   // [N, 64]
    const float* lw  = (const float*)d_in[1];   // [4]
    const float* ew  = (const float*)d_in[2];   // [E]
    const int*   ei  = (const int*)d_in[3];     // [2, E]
    const int* row = ei;                        // sources
    const int* col = ei + N_EDGES;              // targets
    float* out = (float*)d_out;

    // workspace layout (8B alignment for rec at base)
    char* p = (char*)d_ws;
    EdgeRec* rec = (EdgeRec*)p;                 p += (size_t)N_EDGES * sizeof(EdgeRec); // 9.6 MB
    float* x1    = (float*)p;                   p += (size_t)N_NODES * EMB_DIM * 4;     // 25.6 MB
    float* x2    = (float*)p;                   p += (size_t)N_NODES * EMB_DIM * 4;     // 25.6 MB
    float* dinv  = (float*)p;                   p += (size_t)N_NODES * 4;
    int*   count = (int*)p;                     p += (size_t)N_NODES * 4;
    int*   cursor= (int*)p;                     p += (size_t)N_NODES * 4;
    int*   startA= (int*)p;                     p += (size_t)(N_NODES + 1) * 4;
    int*   bsum  = (int*)p;                     p += (size_t)SCAN_NBLK * 4;
    int*   boff  = (int*)p;                     p += (size_t)SCAN_NBLK * 4;

    hipMemsetAsync(dinv,   0, N_NODES * sizeof(float), stream);
    hipMemsetAsync(count,  0, N_NODES * sizeof(int),   stream);
    hipMemsetAsync(cursor, 0, N_NODES * sizeof(int),   stream);

    const int B = 256;
    int egrid = (N_EDGES + B - 1) / B;
    int ngrid = (N_NODES + B - 1) / B;

    hist_kernel<<<egrid, B, 0, stream>>>(ew, col, count, dinv);
    dinv_kernel<<<ngrid, B, 0, stream>>>(dinv);
    scan_partial<<<SCAN_NBLK, B, 0, stream>>>(count, bsum);
    scan_bsum<<<1, 64, 0, stream>>>(bsum, boff, startA);
    scan_final<<<SCAN_NBLK, B, 0, stream>>>(count, boff, startA);
    scatter_kernel<<<egrid, B, 0, stream>>>(row, col, ew, dinv, startA, cursor, rec);

    long rt = (long)N_NODES * EMB_DIM;  // 6.4M threads, one wave per node
    int rgrid = (int)((rt + B - 1) / B);
    prop_kernel<<<rgrid, B, 0, stream>>>(emb, x1, rec, startA, dinv);
    prop_kernel<<<rgrid, B, 0, stream>>>(x1, x2, rec, startA, dinv);
    prop_combine_kernel<<<rgrid, B, 0, stream>>>(x2, emb, x1, rec, startA, dinv, lw, out);
}

// Round 4
// 340.814 us; speedup vs baseline: 2.6537x; 1.1129x over previous
//
#include <hip/hip_runtime.h>

#define N_NODES 100000
#define EMB_DIM 64
#define N_EDGES 1200000
#define N_LAYERS 3

#define SCAN_CHUNK 2048
#define SCAN_NBLK  ((N_NODES + SCAN_CHUNK - 1) / SCAN_CHUNK)   // 49

#define FIX_SCALE 16777216.0f   /* 2^24 */

struct __align__(8) EdgeRec {
    int   s;   // source node
    float w;   // dinv[src] * edge_weight
};

// ---------------------------------------------------------------------------
// packed[c] += (1<<32) | fixedpoint(ew): count in hi32, deg (fixed .24) in lo32
__global__ void hist_kernel(const float* __restrict__ ew,
                            const int* __restrict__ col,
                            unsigned long long* __restrict__ packed) {
    int e = blockIdx.x * blockDim.x + threadIdx.x;
    if (e < N_EDGES) {
        int c = col[e];
        unsigned long long fx = (unsigned long long)(unsigned int)rintf(ew[e] * FIX_SCALE);
        atomicAdd(&packed[c], (1ULL << 32) | fx);
    }
}

// unpack: dinv[n] = rsqrt(deg), count[n] = hi32
__global__ void dinv_kernel(const unsigned long long* __restrict__ packed,
                            float* __restrict__ dinv,
                            int* __restrict__ count) {
    int n = blockIdx.x * blockDim.x + threadIdx.x;
    if (n < N_NODES) {
        unsigned long long p = packed[n];
        count[n] = (int)(p >> 32);
        float d = (float)(unsigned int)(p & 0xFFFFFFFFULL) * (1.0f / FIX_SCALE);
        dinv[n] = (d > 0.0f) ? rsqrtf(d) : 0.0f;
    }
}

// ---- hierarchical scan --------------------------------------------------
// pass A: per-block sums of 2048-element chunks (coalesced)
__global__ void scan_partial(const int* __restrict__ cnt, int* __restrict__ bsum) {
    __shared__ int ws[4];
    int b = blockIdx.x;
    int base = b * SCAN_CHUNK;
    int tid = threadIdx.x;
    int sum = 0;
    for (int i = tid; i < SCAN_CHUNK; i += 256) {
        int idx = base + i;
        if (idx < N_NODES) sum += cnt[idx];
    }
    #pragma unroll
    for (int o = 32; o > 0; o >>= 1) sum += __shfl_xor(sum, o, 64);
    if ((tid & 63) == 0) ws[tid >> 6] = sum;
    __syncthreads();
    if (tid == 0) bsum[b] = ws[0] + ws[1] + ws[2] + ws[3];
}

// pass B: one wave exclusive-scans the 49 block sums; writes total to start[N]
__global__ void scan_bsum(const int* __restrict__ bsum,
                          int* __restrict__ boff,
                          int* __restrict__ start) {
    int tid = threadIdx.x;  // 64 threads
    int s = (tid < SCAN_NBLK) ? bsum[tid] : 0;
    int v = s;
    #pragma unroll
    for (int o = 1; o < 64; o <<= 1) {
        int u = __shfl_up(v, o, 64);
        if (tid >= o) v += u;
    }
    if (tid < SCAN_NBLK) boff[tid] = v - s;   // exclusive
    if (tid == 63) start[N_NODES] = v;        // total == N_EDGES
}

// pass C: block-wide exclusive scan of each chunk + block offset -> start & cursor
__global__ void scan_final(const int* __restrict__ cnt,
                           const int* __restrict__ boff,
                           int* __restrict__ start,
                           int* __restrict__ cursor) {
    __shared__ int ws[4];
    int b = blockIdx.x;
    int base = b * SCAN_CHUNK;
    int tid = threadIdx.x;
    int lane = tid & 63, wid = tid >> 6;

    int idx0 = base + tid * 8;
    int loc[8];
    int s = 0;
    if (idx0 + 8 <= N_NODES) {
        int4 a = *(const int4*)(cnt + idx0);
        int4 c = *(const int4*)(cnt + idx0 + 4);
        loc[0] = a.x; loc[1] = a.y; loc[2] = a.z; loc[3] = a.w;
        loc[4] = c.x; loc[5] = c.y; loc[6] = c.z; loc[7] = c.w;
        s = a.x + a.y + a.z + a.w + c.x + c.y + c.z + c.w;
    } else {
        #pragma unroll
        for (int i = 0; i < 8; ++i) {
            int idx = idx0 + i;
            loc[i] = (idx < N_NODES) ? cnt[idx] : 0;
            s += loc[i];
        }
    }

    int v = s;
    #pragma unroll
    for (int o = 1; o < 64; o <<= 1) {
        int u = __shfl_up(v, o, 64);
        if (lane >= o) v += u;
    }
    if (lane == 63) ws[wid] = v;
    __syncthreads();
    int woff = 0;
    for (int w = 0; w < wid; ++w) woff += ws[w];

    int run = boff[b] + woff + v - s;
    #pragma unroll
    for (int i = 0; i < 8; ++i) {
        int idx = idx0 + i;
        if (idx < N_NODES) { start[idx] = run; cursor[idx] = run; }
        run += loc[i];
    }
}

// scatter edges into CSR order: rec[cursor[c]++] = {row, dinv[row]*ew}
__global__ void scatter_kernel(const int* __restrict__ row,
                               const int* __restrict__ col,
                               const float* __restrict__ ew,
                               const float* __restrict__ dinv,
                               int* __restrict__ cursor,
                               EdgeRec* __restrict__ rec) {
    int e = blockIdx.x * blockDim.x + threadIdx.x;
    if (e < N_EDGES) {
        int c = col[e];
        int r = row[e];
        int pos = atomicAdd(&cursor[c], 1);
        EdgeRec rc;
        rc.s = r;
        rc.w = dinv[r] * ew[e];
        rec[pos] = rc;
    }
}

// xout[n][d] = dinv[n] * sum_j w_j * xin[src_j][d]; one wave per node
__global__ void prop_kernel(const float* __restrict__ xin,
                            float* __restrict__ xout,
                            const EdgeRec* __restrict__ rec,
                            const int* __restrict__ start,
                            const float* __restrict__ dinv) {
    int t = blockIdx.x * blockDim.x + threadIdx.x;
    int n = t >> 6;
    int d = t & 63;
    if (n >= N_NODES) return;

    int s = start[n], e = start[n + 1];
    float acc = 0.0f;
    int j = s;
    for (; j + 4 <= e; j += 4) {
        EdgeRec r0 = rec[j], r1 = rec[j + 1], r2 = rec[j + 2], r3 = rec[j + 3];
        float v0 = xin[r0.s * EMB_DIM + d];
        float v1 = xin[r1.s * EMB_DIM + d];
        float v2 = xin[r2.s * EMB_DIM + d];
        float v3 = xin[r3.s * EMB_DIM + d];
        acc += r0.w * v0;
        acc += r1.w * v1;
        acc += r2.w * v2;
        acc += r3.w * v3;
    }
    for (; j < e; ++j) {
        EdgeRec r = rec[j];
        acc += r.w * xin[r.s * EMB_DIM + d];
    }
    xout[t] = dinv[n] * acc;
}

// last propagation fused with weighted layer-combine + row L2-normalize
__global__ void prop_combine_kernel(const float* __restrict__ x2,     // input to layer 3
                                    const float* __restrict__ x0,     // emb
                                    const float* __restrict__ x1,
                                    const EdgeRec* __restrict__ rec,
                                    const int* __restrict__ start,
                                    const float* __restrict__ dinv,
                                    const float* __restrict__ lw,
                                    float* __restrict__ out) {
    int t = blockIdx.x * blockDim.x + threadIdx.x;
    int n = t >> 6;
    int d = t & 63;
    if (n >= N_NODES) return;

    int s = start[n], e = start[n + 1];
    float acc = 0.0f;
    int j = s;
    for (; j + 4 <= e; j += 4) {
        EdgeRec r0 = rec[j], r1 = rec[j + 1], r2 = rec[j + 2], r3 = rec[j + 3];
        float v0 = x2[r0.s * EMB_DIM + d];
        float v1 = x2[r1.s * EMB_DIM + d];
        float v2 = x2[r2.s * EMB_DIM + d];
        float v3 = x2[r3.s * EMB_DIM + d];
        acc += r0.w * v0;
        acc += r1.w * v1;
        acc += r2.w * v2;
        acc += r3.w * v3;
    }
    for (; j < e; ++j) {
        EdgeRec r = rec[j];
        acc += r.w * x2[r.s * EMB_DIM + d];
    }
    float x3v = dinv[n] * acc;

    float w0 = lw[0], w1 = lw[1], w2 = lw[2], w3 = lw[3];
    float m = fmaxf(fmaxf(w0, w1), fmaxf(w2, w3));
    float e0 = expf(w0 - m), e1 = expf(w1 - m), e2 = expf(w2 - m), e3 = expf(w3 - m);
    float inv_s = 1.0f / (e0 + e1 + e2 + e3);

    float v = (e0 * x0[t] + e1 * x1[t] + e2 * x2[t] + e3 * x3v) * inv_s;

    float sq = v * v;
    #pragma unroll
    for (int o = 32; o > 0; o >>= 1) sq += __shfl_xor(sq, o, 64);
    float nrm = fmaxf(sqrtf(sq), 1e-12f);
    out[t] = v / nrm;
}

// ---------------------------------------------------------------------------
extern "C" void kernel_launch(void* const* d_in, const int* in_sizes, int n_in,
                              void* d_out, int out_size, void* d_ws, size_t ws_size,
                              hipStream_t stream) {
    const float* emb = (const float*)d_in[0];   // [N, 64]
    const float* lw  = (const float*)d_in[1];   // [4]
    const float* ew  = (const float*)d_in[2];   // [E]
    const int*   ei  = (const int*)d_in[3];     // [2, E]
    const int* row = ei;                        // sources
    const int* col = ei + N_EDGES;              // targets
    float* out = (float*)d_out;

    // workspace layout (8B-aligned pieces)
    char* p = (char*)d_ws;
    EdgeRec* rec = (EdgeRec*)p;                 p += (size_t)N_EDGES * sizeof(EdgeRec); // 9.6 MB
    float* x1    = (float*)p;                   p += (size_t)N_NODES * EMB_DIM * 4;     // 25.6 MB
    float* x2    = (float*)p;                   p += (size_t)N_NODES * EMB_DIM * 4;     // 25.6 MB
    unsigned long long* packed = (unsigned long long*)p; p += (size_t)N_NODES * 8;      // 0.8 MB
    float* dinv  = (float*)p;                   p += (size_t)N_NODES * 4;
    int*   count = (int*)p;                     p += (size_t)N_NODES * 4;
    int*   cursor= (int*)p;                     p += (size_t)N_NODES * 4;
    int*   startA= (int*)p;                     p += (size_t)(N_NODES + 8) * 4;
    int*   bsum  = (int*)p;                     p += (size_t)SCAN_NBLK * 4;
    int*   boff  = (int*)p;                     p += (size_t)SCAN_NBLK * 4;

    hipMemsetAsync(packed, 0, N_NODES * sizeof(unsigned long long), stream);

    const int B = 256;
    int egrid = (N_EDGES + B - 1) / B;
    int ngrid = (N_NODES + B - 1) / B;

    hist_kernel<<<egrid, B, 0, stream>>>(ew, col, packed);
    dinv_kernel<<<ngrid, B, 0, stream>>>(packed, dinv, count);
    scan_partial<<<SCAN_NBLK, B, 0, stream>>>(count, bsum);
    scan_bsum<<<1, 64, 0, stream>>>(bsum, boff, startA);
    scan_final<<<SCAN_NBLK, B, 0, stream>>>(count, boff, startA, cursor);
    scatter_kernel<<<egrid, B, 0, stream>>>(row, col, ew, dinv, cursor, rec);

    long rt = (long)N_NODES * EMB_DIM;  // 6.4M threads, one wave per node
    int rgrid = (int)((rt + B - 1) / B);
    prop_kernel<<<rgrid, B, 0, stream>>>(emb, x1, rec, startA, dinv);
    prop_kernel<<<rgrid, B, 0, stream>>>(x1, x2, rec, startA, dinv);
    prop_combine_kernel<<<rgrid, B, 0, stream>>>(x2, emb, x1, rec, startA, dinv, lw, out);
}

// Round 5
// 261.784 us; speedup vs baseline: 3.4549x; 1.3019x over previous
//
#include <hip/hip_runtime.h>

#define N_NODES 100000
#define EMB_DIM 64
#define N_EDGES 1200000

#define BSHIFT  7
#define BNODES  128
#define NBUCKET ((N_NODES + BNODES - 1) / BNODES)   // 782
#define EPB     6144                                 // edges per binning block
#define NBLK_BIN ((N_EDGES + EPB - 1) / EPB)         // 196

struct __align__(8) EdgeRec {
    int   s;   // source node
    float w;   // dinv[src] * edge_weight
};

struct __align__(8) BinRec {
    unsigned meta;  // src (bits 0..19) | local_dst (bits 20..26)
    float    ew;
};

// ---------------------------------------------------------------------------
// Phase A: per-block LDS histogram of dst-buckets -> global bucket counts
__global__ void bin_hist(const int* __restrict__ col, int* __restrict__ bucket_cnt) {
    __shared__ int h[NBUCKET];
    int tid = threadIdx.x;
    for (int i = tid; i < NBUCKET; i += 256) h[i] = 0;
    __syncthreads();
    int base = blockIdx.x * EPB;
    int end = base + EPB; if (end > N_EDGES) end = N_EDGES;
    for (int e = base + tid; e < end; e += 256)
        atomicAdd(&h[col[e] >> BSHIFT], 1);
    __syncthreads();
    for (int i = tid; i < NBUCKET; i += 256)
        if (h[i]) atomicAdd(&bucket_cnt[i], h[i]);
}

// Phase B: exclusive scan of 782 bucket counts -> base & cursor; start[N]=E
__global__ void bucket_scan(const int* __restrict__ cnt,
                            int* __restrict__ base,
                            int* __restrict__ cursor,
                            int* __restrict__ start) {
    __shared__ int ws[16];
    int t = threadIdx.x;            // 1024 threads
    int lane = t & 63, wid = t >> 6;
    int v = (t < NBUCKET) ? cnt[t] : 0;
    int inc = v;
    #pragma unroll
    for (int o = 1; o < 64; o <<= 1) {
        int u = __shfl_up(inc, o, 64);
        if (lane >= o) inc += u;
    }
    if (lane == 63) ws[wid] = inc;
    __syncthreads();
    int woff = 0;
    for (int w = 0; w < wid; ++w) woff += ws[w];
    int excl = woff + inc - v;
    if (t < NBUCKET) { base[t] = excl; cursor[t] = excl; }
    if (t == 0) start[N_NODES] = N_EDGES;
}

// Phase C: bin edges into bucket-contiguous storage (per-block range reserve)
__global__ void bin_scatter(const int* __restrict__ row,
                            const int* __restrict__ col,
                            const float* __restrict__ ew,
                            int* __restrict__ bucket_cursor,
                            BinRec* __restrict__ binned) {
    __shared__ int hcnt[NBUCKET];
    __shared__ int hbase[NBUCKET];
    int tid = threadIdx.x;
    for (int i = tid; i < NBUCKET; i += 256) hcnt[i] = 0;
    __syncthreads();
    int base = blockIdx.x * EPB;
    int end = base + EPB; if (end > N_EDGES) end = N_EDGES;
    for (int e = base + tid; e < end; e += 256)
        atomicAdd(&hcnt[col[e] >> BSHIFT], 1);
    __syncthreads();
    for (int i = tid; i < NBUCKET; i += 256) {
        int c = hcnt[i];
        hbase[i] = c ? atomicAdd(&bucket_cursor[i], c) : 0;
        hcnt[i] = 0;   // reuse as local cursor (same thread owns index i)
    }
    __syncthreads();
    for (int e = base + tid; e < end; e += 256) {
        int c = col[e];
        int b = c >> BSHIFT;
        int rk = atomicAdd(&hcnt[b], 1);
        BinRec r;
        r.meta = (unsigned)row[e] | ((unsigned)(c & (BNODES - 1)) << 20);
        r.ew = ew[e];
        binned[hbase[b] + rk] = r;
    }
}

// Phase D1: per-bucket node counts + float deg (LDS), scan -> start[], dinv[]
__global__ void bucket_stats(const BinRec* __restrict__ binned,
                             const int* __restrict__ bucket_base,
                             const int* __restrict__ bucket_cnt,
                             float* __restrict__ dinv,
                             int* __restrict__ start) {
    __shared__ int   cnt[BNODES];
    __shared__ float deg[BNODES];
    __shared__ int   wsum[2];
    int b = blockIdx.x;
    int tid = threadIdx.x;
    if (tid < BNODES) { cnt[tid] = 0; deg[tid] = 0.0f; }
    __syncthreads();
    int s = bucket_base[b], n = bucket_cnt[b];
    for (int i = tid; i < n; i += 256) {
        BinRec r = binned[s + i];
        int l = r.meta >> 20;
        atomicAdd(&cnt[l], 1);
        atomicAdd(&deg[l], r.ew);
    }
    __syncthreads();
    if (tid < BNODES) {
        int lane = tid & 63, wid = tid >> 6;
        int v = cnt[tid];
        int inc = v;
        #pragma unroll
        for (int o = 1; o < 64; o <<= 1) {
            int u = __shfl_up(inc, o, 64);
            if (lane >= o) inc += u;
        }
        if (lane == 63) wsum[wid] = inc;
        __syncthreads();
        int excl = inc - v + ((wid == 1) ? wsum[0] : 0);
        int node = (b << BSHIFT) + tid;
        if (node < N_NODES) {
            start[node] = s + excl;
            float d = deg[tid];
            dinv[node] = (d > 0.0f) ? rsqrtf(d) : 0.0f;
        }
    }
}

// Phase D2: scatter edges within bucket window -> final rec {src, dinv[src]*ew}
__global__ void bucket_scatter(const BinRec* __restrict__ binned,
                               const int* __restrict__ bucket_base,
                               const int* __restrict__ bucket_cnt,
                               const int* __restrict__ start,
                               const float* __restrict__ dinv,
                               EdgeRec* __restrict__ rec) {
    __shared__ int cur[BNODES];
    int b = blockIdx.x;
    int tid = threadIdx.x;
    if (tid < BNODES) {
        int node = (b << BSHIFT) + tid;
        cur[tid] = (node < N_NODES) ? start[node] : 0;
    }
    __syncthreads();
    int s = bucket_base[b], n = bucket_cnt[b];
    for (int i = tid; i < n; i += 256) {
        BinRec r = binned[s + i];
        int l = r.meta >> 20;
        int src = (int)(r.meta & 0xFFFFFu);
        int pos = atomicAdd(&cur[l], 1);
        EdgeRec o;
        o.s = src;
        o.w = dinv[src] * r.ew;
        rec[pos] = o;
    }
}

// ---------------------------------------------------------------------------
// xout[n][d] = dinv[n] * sum_j w_j * xin[src_j][d]; one wave per node
__global__ void prop_kernel(const float* __restrict__ xin,
                            float* __restrict__ xout,
                            const EdgeRec* __restrict__ rec,
                            const int* __restrict__ start,
                            const float* __restrict__ dinv) {
    int t = blockIdx.x * blockDim.x + threadIdx.x;
    int n = t >> 6;
    int d = t & 63;
    if (n >= N_NODES) return;

    int s = start[n], e = start[n + 1];
    float acc = 0.0f;
    int j = s;
    for (; j + 4 <= e; j += 4) {
        EdgeRec r0 = rec[j], r1 = rec[j + 1], r2 = rec[j + 2], r3 = rec[j + 3];
        float v0 = xin[r0.s * EMB_DIM + d];
        float v1 = xin[r1.s * EMB_DIM + d];
        float v2 = xin[r2.s * EMB_DIM + d];
        float v3 = xin[r3.s * EMB_DIM + d];
        acc += r0.w * v0;
        acc += r1.w * v1;
        acc += r2.w * v2;
        acc += r3.w * v3;
    }
    for (; j < e; ++j) {
        EdgeRec r = rec[j];
        acc += r.w * xin[r.s * EMB_DIM + d];
    }
    xout[t] = dinv[n] * acc;
}

// last propagation fused with weighted layer-combine + row L2-normalize
__global__ void prop_combine_kernel(const float* __restrict__ x2,
                                    const float* __restrict__ x0,
                                    const float* __restrict__ x1,
                                    const EdgeRec* __restrict__ rec,
                                    const int* __restrict__ start,
                                    const float* __restrict__ dinv,
                                    const float* __restrict__ lw,
                                    float* __restrict__ out) {
    int t = blockIdx.x * blockDim.x + threadIdx.x;
    int n = t >> 6;
    int d = t & 63;
    if (n >= N_NODES) return;

    int s = start[n], e = start[n + 1];
    float acc = 0.0f;
    int j = s;
    for (; j + 4 <= e; j += 4) {
        EdgeRec r0 = rec[j], r1 = rec[j + 1], r2 = rec[j + 2], r3 = rec[j + 3];
        float v0 = x2[r0.s * EMB_DIM + d];
        float v1 = x2[r1.s * EMB_DIM + d];
        float v2 = x2[r2.s * EMB_DIM + d];
        float v3 = x2[r3.s * EMB_DIM + d];
        acc += r0.w * v0;
        acc += r1.w * v1;
        acc += r2.w * v2;
        acc += r3.w * v3;
    }
    for (; j < e; ++j) {
        EdgeRec r = rec[j];
        acc += r.w * x2[r.s * EMB_DIM + d];
    }
    float x3v = dinv[n] * acc;

    float w0 = lw[0], w1 = lw[1], w2 = lw[2], w3 = lw[3];
    float m = fmaxf(fmaxf(w0, w1), fmaxf(w2, w3));
    float e0 = expf(w0 - m), e1 = expf(w1 - m), e2 = expf(w2 - m), e3 = expf(w3 - m);
    float inv_s = 1.0f / (e0 + e1 + e2 + e3);

    float v = (e0 * x0[t] + e1 * x1[t] + e2 * x2[t] + e3 * x3v) * inv_s;

    float sq = v * v;
    #pragma unroll
    for (int o = 32; o > 0; o >>= 1) sq += __shfl_xor(sq, o, 64);
    float nrm = fmaxf(sqrtf(sq), 1e-12f);
    out[t] = v / nrm;
}

// ---------------------------------------------------------------------------
extern "C" void kernel_launch(void* const* d_in, const int* in_sizes, int n_in,
                              void* d_out, int out_size, void* d_ws, size_t ws_size,
                              hipStream_t stream) {
    const float* emb = (const float*)d_in[0];   // [N, 64]
    const float* lw  = (const float*)d_in[1];   // [4]
    const float* ew  = (const float*)d_in[2];   // [E]
    const int*   ei  = (const int*)d_in[3];     // [2, E]
    const int* row = ei;                        // sources
    const int* col = ei + N_EDGES;              // targets
    float* out = (float*)d_out;

    // workspace layout (8B-aligned pieces)
    char* p = (char*)d_ws;
    BinRec*  binned = (BinRec*)p;               p += (size_t)N_EDGES * sizeof(BinRec);  // 9.6 MB
    EdgeRec* rec    = (EdgeRec*)p;              p += (size_t)N_EDGES * sizeof(EdgeRec); // 9.6 MB
    float* x1    = (float*)p;                   p += (size_t)N_NODES * EMB_DIM * 4;     // 25.6 MB
    float* x2    = (float*)p;                   p += (size_t)N_NODES * EMB_DIM * 4;     // 25.6 MB
    float* dinv  = (float*)p;                   p += (size_t)N_NODES * 4;
    int*   startA= (int*)p;                     p += (size_t)(N_NODES + 8) * 4;
    int*   bucket_cnt    = (int*)p;             p += (size_t)NBUCKET * 4;
    int*   bucket_base   = (int*)p;             p += (size_t)NBUCKET * 4;
    int*   bucket_cursor = (int*)p;             p += (size_t)NBUCKET * 4;

    hipMemsetAsync(bucket_cnt, 0, NBUCKET * sizeof(int), stream);

    const int B = 256;

    bin_hist<<<NBLK_BIN, B, 0, stream>>>(col, bucket_cnt);
    bucket_scan<<<1, 1024, 0, stream>>>(bucket_cnt, bucket_base, bucket_cursor, startA);
    bin_scatter<<<NBLK_BIN, B, 0, stream>>>(row, col, ew, bucket_cursor, binned);
    bucket_stats<<<NBUCKET, B, 0, stream>>>(binned, bucket_base, bucket_cnt, dinv, startA);
    bucket_scatter<<<NBUCKET, B, 0, stream>>>(binned, bucket_base, bucket_cnt, startA, dinv, rec);

    long rt = (long)N_NODES * EMB_DIM;  // 6.4M threads, one wave per node
    int rgrid = (int)((rt + B - 1) / B);
    prop_kernel<<<rgrid, B, 0, stream>>>(emb, x1, rec, startA, dinv);
    prop_kernel<<<rgrid, B, 0, stream>>>(x1, x2, rec, startA, dinv);
    prop_combine_kernel<<<rgrid, B, 0, stream>>>(x2, emb, x1, rec, startA, dinv, lw, out);
}

// Round 6
// 257.114 us; speedup vs baseline: 3.5176x; 1.0182x over previous
//
#include <hip/hip_runtime.h>

#define N_NODES 100000
#define EMB_DIM 64
#define N_EDGES 1200000

#define BSHIFT  7
#define BNODES  128
#define NBUCKET ((N_NODES + BNODES - 1) / BNODES)   // 782
#define EPB     6144                                 // edges per binning block
#define NBLK_BIN ((N_EDGES + EPB - 1) / EPB)         // 196

struct __align__(8) EdgeRec {
    int   s;   // source node
    float w;   // dinv[src] * edge_weight
};

struct __align__(8) BinRec {
    unsigned meta;  // src (bits 0..19) | local_dst (bits 20..26)
    float    ew;
};

// bf16 helpers (RNE)
__device__ __forceinline__ unsigned short f2bf(float f) {
    unsigned u = __float_as_uint(f);
    u += 0x7FFFu + ((u >> 16) & 1u);
    return (unsigned short)(u >> 16);
}
__device__ __forceinline__ float bf2f(unsigned short h) {
    return __uint_as_float((unsigned)h << 16);
}

// ---------------------------------------------------------------------------
// emb fp32 -> bf16 copy (8 elems/thread, fully coalesced)
__global__ void cvt_emb(const float* __restrict__ in, unsigned short* __restrict__ out) {
    int t = blockIdx.x * blockDim.x + threadIdx.x;
    long base = (long)t * 8;
    if (base + 8 <= (long)N_NODES * EMB_DIM) {
        float4 a = *(const float4*)(in + base);
        float4 b = *(const float4*)(in + base + 4);
        uint4 o;
        o.x = (unsigned)f2bf(a.x) | ((unsigned)f2bf(a.y) << 16);
        o.y = (unsigned)f2bf(a.z) | ((unsigned)f2bf(a.w) << 16);
        o.z = (unsigned)f2bf(b.x) | ((unsigned)f2bf(b.y) << 16);
        o.w = (unsigned)f2bf(b.z) | ((unsigned)f2bf(b.w) << 16);
        *(uint4*)(out + base) = o;
    }
}

// ---------------------------------------------------------------------------
// Phase A: per-block LDS histogram of dst-buckets -> global bucket counts
__global__ void bin_hist(const int* __restrict__ col, int* __restrict__ bucket_cnt) {
    __shared__ int h[NBUCKET];
    int tid = threadIdx.x;
    for (int i = tid; i < NBUCKET; i += 256) h[i] = 0;
    __syncthreads();
    int base = blockIdx.x * EPB;
    int end = base + EPB; if (end > N_EDGES) end = N_EDGES;
    for (int e = base + tid; e < end; e += 256)
        atomicAdd(&h[col[e] >> BSHIFT], 1);
    __syncthreads();
    for (int i = tid; i < NBUCKET; i += 256)
        if (h[i]) atomicAdd(&bucket_cnt[i], h[i]);
}

// Phase B: exclusive scan of 782 bucket counts -> base & cursor; start[N]=E
__global__ void bucket_scan(const int* __restrict__ cnt,
                            int* __restrict__ base,
                            int* __restrict__ cursor,
                            int* __restrict__ start) {
    __shared__ int ws[16];
    int t = threadIdx.x;            // 1024 threads
    int lane = t & 63, wid = t >> 6;
    int v = (t < NBUCKET) ? cnt[t] : 0;
    int inc = v;
    #pragma unroll
    for (int o = 1; o < 64; o <<= 1) {
        int u = __shfl_up(inc, o, 64);
        if (lane >= o) inc += u;
    }
    if (lane == 63) ws[wid] = inc;
    __syncthreads();
    int woff = 0;
    for (int w = 0; w < wid; ++w) woff += ws[w];
    int excl = woff + inc - v;
    if (t < NBUCKET) { base[t] = excl; cursor[t] = excl; }
    if (t == 0) start[N_NODES] = N_EDGES;
}

// Phase C: bin edges into bucket-contiguous storage (per-block range reserve)
__global__ void bin_scatter(const int* __restrict__ row,
                            const int* __restrict__ col,
                            const float* __restrict__ ew,
                            int* __restrict__ bucket_cursor,
                            BinRec* __restrict__ binned) {
    __shared__ int hcnt[NBUCKET];
    __shared__ int hbase[NBUCKET];
    int tid = threadIdx.x;
    for (int i = tid; i < NBUCKET; i += 256) hcnt[i] = 0;
    __syncthreads();
    int base = blockIdx.x * EPB;
    int end = base + EPB; if (end > N_EDGES) end = N_EDGES;
    for (int e = base + tid; e < end; e += 256)
        atomicAdd(&hcnt[col[e] >> BSHIFT], 1);
    __syncthreads();
    for (int i = tid; i < NBUCKET; i += 256) {
        int c = hcnt[i];
        hbase[i] = c ? atomicAdd(&bucket_cursor[i], c) : 0;
        hcnt[i] = 0;   // reuse as local cursor (same thread owns index i)
    }
    __syncthreads();
    for (int e = base + tid; e < end; e += 256) {
        int c = col[e];
        int b = c >> BSHIFT;
        int rk = atomicAdd(&hcnt[b], 1);
        BinRec r;
        r.meta = (unsigned)row[e] | ((unsigned)(c & (BNODES - 1)) << 20);
        r.ew = ew[e];
        binned[hbase[b] + rk] = r;
    }
}

// Phase D1: per-bucket node counts + float deg (LDS), scan -> start[], dinv[]
__global__ void bucket_stats(const BinRec* __restrict__ binned,
                             const int* __restrict__ bucket_base,
                             const int* __restrict__ bucket_cnt,
                             float* __restrict__ dinv,
                             int* __restrict__ start) {
    __shared__ int   cnt[BNODES];
    __shared__ float deg[BNODES];
    __shared__ int   wsum[2];
    int b = blockIdx.x;
    int tid = threadIdx.x;
    if (tid < BNODES) { cnt[tid] = 0; deg[tid] = 0.0f; }
    __syncthreads();
    int s = bucket_base[b], n = bucket_cnt[b];
    for (int i = tid; i < n; i += 256) {
        BinRec r = binned[s + i];
        int l = r.meta >> 20;
        atomicAdd(&cnt[l], 1);
        atomicAdd(&deg[l], r.ew);
    }
    __syncthreads();
    if (tid < BNODES) {
        int lane = tid & 63, wid = tid >> 6;
        int v = cnt[tid];
        int inc = v;
        #pragma unroll
        for (int o = 1; o < 64; o <<= 1) {
            int u = __shfl_up(inc, o, 64);
            if (lane >= o) inc += u;
        }
        if (lane == 63) wsum[wid] = inc;
        __syncthreads();
        int excl = inc - v + ((wid == 1) ? wsum[0] : 0);
        int node = (b << BSHIFT) + tid;
        if (node < N_NODES) {
            start[node] = s + excl;
            float d = deg[tid];
            dinv[node] = (d > 0.0f) ? rsqrtf(d) : 0.0f;
        }
    }
}

// Phase D2: scatter edges within bucket window -> final rec {src, dinv[src]*ew}
__global__ void bucket_scatter(const BinRec* __restrict__ binned,
                               const int* __restrict__ bucket_base,
                               const int* __restrict__ bucket_cnt,
                               const int* __restrict__ start,
                               const float* __restrict__ dinv,
                               EdgeRec* __restrict__ rec) {
    __shared__ int cur[BNODES];
    int b = blockIdx.x;
    int tid = threadIdx.x;
    if (tid < BNODES) {
        int node = (b << BSHIFT) + tid;
        cur[tid] = (node < N_NODES) ? start[node] : 0;
    }
    __syncthreads();
    int s = bucket_base[b], n = bucket_cnt[b];
    for (int i = tid; i < n; i += 256) {
        BinRec r = binned[s + i];
        int l = r.meta >> 20;
        int src = (int)(r.meta & 0xFFFFFu);
        int pos = atomicAdd(&cur[l], 1);
        EdgeRec o;
        o.s = src;
        o.w = dinv[src] * r.ew;
        rec[pos] = o;
    }
}

// ---------------------------------------------------------------------------
// xout[n][d] = bf16( dinv[n] * sum_j w_j * xin[src_j][d] ); one wave per node
__global__ void prop_kernel(const unsigned short* __restrict__ xin,
                            unsigned short* __restrict__ xout,
                            const EdgeRec* __restrict__ rec,
                            const int* __restrict__ start,
                            const float* __restrict__ dinv) {
    int t = blockIdx.x * blockDim.x + threadIdx.x;
    int n = t >> 6;
    int d = t & 63;
    if (n >= N_NODES) return;

    int s = start[n], e = start[n + 1];
    float acc = 0.0f;
    int j = s;
    for (; j + 4 <= e; j += 4) {
        EdgeRec r0 = rec[j], r1 = rec[j + 1], r2 = rec[j + 2], r3 = rec[j + 3];
        float v0 = bf2f(xin[r0.s * EMB_DIM + d]);
        float v1 = bf2f(xin[r1.s * EMB_DIM + d]);
        float v2 = bf2f(xin[r2.s * EMB_DIM + d]);
        float v3 = bf2f(xin[r3.s * EMB_DIM + d]);
        acc += r0.w * v0;
        acc += r1.w * v1;
        acc += r2.w * v2;
        acc += r3.w * v3;
    }
    for (; j < e; ++j) {
        EdgeRec r = rec[j];
        acc += r.w * bf2f(xin[r.s * EMB_DIM + d]);
    }
    xout[t] = f2bf(dinv[n] * acc);
}

// last propagation fused with weighted layer-combine + row L2-normalize
__global__ void prop_combine_kernel(const unsigned short* __restrict__ x2h,  // bf16, gathered
                                    const float* __restrict__ x0,            // emb fp32, seq
                                    const unsigned short* __restrict__ x1h,  // bf16, seq
                                    const EdgeRec* __restrict__ rec,
                                    const int* __restrict__ start,
                                    const float* __restrict__ dinv,
                                    const float* __restrict__ lw,
                                    float* __restrict__ out) {
    int t = blockIdx.x * blockDim.x + threadIdx.x;
    int n = t >> 6;
    int d = t & 63;
    if (n >= N_NODES) return;

    int s = start[n], e = start[n + 1];
    float acc = 0.0f;
    int j = s;
    for (; j + 4 <= e; j += 4) {
        EdgeRec r0 = rec[j], r1 = rec[j + 1], r2 = rec[j + 2], r3 = rec[j + 3];
        float v0 = bf2f(x2h[r0.s * EMB_DIM + d]);
        float v1 = bf2f(x2h[r1.s * EMB_DIM + d]);
        float v2 = bf2f(x2h[r2.s * EMB_DIM + d]);
        float v3 = bf2f(x2h[r3.s * EMB_DIM + d]);
        acc += r0.w * v0;
        acc += r1.w * v1;
        acc += r2.w * v2;
        acc += r3.w * v3;
    }
    for (; j < e; ++j) {
        EdgeRec r = rec[j];
        acc += r.w * bf2f(x2h[r.s * EMB_DIM + d]);
    }
    float x3v = dinv[n] * acc;

    float w0 = lw[0], w1 = lw[1], w2 = lw[2], w3 = lw[3];
    float m = fmaxf(fmaxf(w0, w1), fmaxf(w2, w3));
    float e0 = expf(w0 - m), e1 = expf(w1 - m), e2 = expf(w2 - m), e3 = expf(w3 - m);
    float inv_s = 1.0f / (e0 + e1 + e2 + e3);

    float v = (e0 * x0[t] + e1 * bf2f(x1h[t]) + e2 * bf2f(x2h[t]) + e3 * x3v) * inv_s;

    float sq = v * v;
    #pragma unroll
    for (int o = 32; o > 0; o >>= 1) sq += __shfl_xor(sq, o, 64);
    float nrm = fmaxf(sqrtf(sq), 1e-12f);
    out[t] = v / nrm;
}

// ---------------------------------------------------------------------------
extern "C" void kernel_launch(void* const* d_in, const int* in_sizes, int n_in,
                              void* d_out, int out_size, void* d_ws, size_t ws_size,
                              hipStream_t stream) {
    const float* emb = (const float*)d_in[0];   // [N, 64]
    const float* lw  = (const float*)d_in[1];   // [4]
    const float* ew  = (const float*)d_in[2];   // [E]
    const int*   ei  = (const int*)d_in[3];     // [2, E]
    const int* row = ei;                        // sources
    const int* col = ei + N_EDGES;              // targets
    float* out = (float*)d_out;

    // workspace layout (8B-aligned pieces)
    char* p = (char*)d_ws;
    BinRec*  binned = (BinRec*)p;               p += (size_t)N_EDGES * sizeof(BinRec);  // 9.6 MB
    EdgeRec* rec    = (EdgeRec*)p;              p += (size_t)N_EDGES * sizeof(EdgeRec); // 9.6 MB
    unsigned short* embh = (unsigned short*)p;  p += (size_t)N_NODES * EMB_DIM * 2;     // 12.8 MB
    unsigned short* x1h  = (unsigned short*)p;  p += (size_t)N_NODES * EMB_DIM * 2;     // 12.8 MB
    unsigned short* x2h  = (unsigned short*)p;  p += (size_t)N_NODES * EMB_DIM * 2;     // 12.8 MB
    float* dinv  = (float*)p;                   p += (size_t)N_NODES * 4;
    int*   startA= (int*)p;                     p += (size_t)(N_NODES + 8) * 4;
    int*   bucket_cnt    = (int*)p;             p += (size_t)NBUCKET * 4;
    int*   bucket_base   = (int*)p;             p += (size_t)NBUCKET * 4;
    int*   bucket_cursor = (int*)p;             p += (size_t)NBUCKET * 4;

    hipMemsetAsync(bucket_cnt, 0, NBUCKET * sizeof(int), stream);

    const int B = 256;

    cvt_emb<<<(N_NODES * EMB_DIM / 8 + B - 1) / B, B, 0, stream>>>(emb, embh);
    bin_hist<<<NBLK_BIN, B, 0, stream>>>(col, bucket_cnt);
    bucket_scan<<<1, 1024, 0, stream>>>(bucket_cnt, bucket_base, bucket_cursor, startA);
    bin_scatter<<<NBLK_BIN, B, 0, stream>>>(row, col, ew, bucket_cursor, binned);
    bucket_stats<<<NBUCKET, B, 0, stream>>>(binned, bucket_base, bucket_cnt, dinv, startA);
    bucket_scatter<<<NBUCKET, B, 0, stream>>>(binned, bucket_base, bucket_cnt, startA, dinv, rec);

    long rt = (long)N_NODES * EMB_DIM;  // 6.4M threads, one wave per node
    int rgrid = (int)((rt + B - 1) / B);
    prop_kernel<<<rgrid, B, 0, stream>>>(embh, x1h, rec, startA, dinv);
    prop_kernel<<<rgrid, B, 0, stream>>>(x1h, x2h, rec, startA, dinv);
    prop_combine_kernel<<<rgrid, B, 0, stream>>>(x2h, emb, x1h, rec, startA, dinv, lw, out);
}

// Round 7
// 199.894 us; speedup vs baseline: 4.5245x; 1.2862x over previous
//
#include <hip/hip_runtime.h>

#define N_NODES 100000
#define EMB_DIM 64
#define N_EDGES 1200000

#define BSHIFT  7
#define BNODES  128
#define NBUCKET ((N_NODES + BNODES - 1) / BNODES)   // 782
#define EPB     6144                                 // edges per binning block
#define NBLK_BIN ((N_EDGES + EPB - 1) / EPB)         // 196

#define DBINS 512
#define DNPB  1024
#define NBLK_DEG ((N_NODES + DNPB - 1) / DNPB)       // 98

struct __align__(8) EdgeRec {
    int   s;   // source node
    float w;   // dinv[src] * edge_weight
};

struct __align__(8) BinRec {
    unsigned meta;  // src (bits 0..19) | local_dst (bits 20..26)
    float    ew;
};

// bf16 helpers (RNE)
__device__ __forceinline__ unsigned short f2bf(float f) {
    unsigned u = __float_as_uint(f);
    u += 0x7FFFu + ((u >> 16) & 1u);
    return (unsigned short)(u >> 16);
}
__device__ __forceinline__ float bf2f(unsigned short h) {
    return __uint_as_float((unsigned)h << 16);
}

// ---------------------------------------------------------------------------
// emb fp32 -> bf16 copy (8 elems/thread, fully coalesced)
__global__ void cvt_emb(const float* __restrict__ in, unsigned short* __restrict__ out) {
    int t = blockIdx.x * blockDim.x + threadIdx.x;
    long base = (long)t * 8;
    if (base + 8 <= (long)N_NODES * EMB_DIM) {
        float4 a = *(const float4*)(in + base);
        float4 b = *(const float4*)(in + base + 4);
        uint4 o;
        o.x = (unsigned)f2bf(a.x) | ((unsigned)f2bf(a.y) << 16);
        o.y = (unsigned)f2bf(a.z) | ((unsigned)f2bf(a.w) << 16);
        o.z = (unsigned)f2bf(b.x) | ((unsigned)f2bf(b.y) << 16);
        o.w = (unsigned)f2bf(b.z) | ((unsigned)f2bf(b.w) << 16);
        *(uint4*)(out + base) = o;
    }
}

// ---------------------------------------------------------------------------
// Phase A: per-block LDS histogram of dst-buckets -> global bucket counts
__global__ void bin_hist(const int* __restrict__ col, int* __restrict__ bucket_cnt) {
    __shared__ int h[NBUCKET];
    int tid = threadIdx.x;
    for (int i = tid; i < NBUCKET; i += 256) h[i] = 0;
    __syncthreads();
    int base = blockIdx.x * EPB;
    int end = base + EPB; if (end > N_EDGES) end = N_EDGES;
    for (int e = base + tid; e < end; e += 256)
        atomicAdd(&h[col[e] >> BSHIFT], 1);
    __syncthreads();
    for (int i = tid; i < NBUCKET; i += 256)
        if (h[i]) atomicAdd(&bucket_cnt[i], h[i]);
}

// Phase B: exclusive scan of 782 bucket counts -> base & cursor; start[N]=E
__global__ void bucket_scan(const int* __restrict__ cnt,
                            int* __restrict__ base,
                            int* __restrict__ cursor,
                            int* __restrict__ start) {
    __shared__ int ws[16];
    int t = threadIdx.x;            // 1024 threads
    int lane = t & 63, wid = t >> 6;
    int v = (t < NBUCKET) ? cnt[t] : 0;
    int inc = v;
    #pragma unroll
    for (int o = 1; o < 64; o <<= 1) {
        int u = __shfl_up(inc, o, 64);
        if (lane >= o) inc += u;
    }
    if (lane == 63) ws[wid] = inc;
    __syncthreads();
    int woff = 0;
    for (int w = 0; w < wid; ++w) woff += ws[w];
    int excl = woff + inc - v;
    if (t < NBUCKET) { base[t] = excl; cursor[t] = excl; }
    if (t == 0) start[N_NODES] = N_EDGES;
}

// Phase C: bin edges into bucket-contiguous storage (per-block range reserve)
__global__ void bin_scatter(const int* __restrict__ row,
                            const int* __restrict__ col,
                            const float* __restrict__ ew,
                            int* __restrict__ bucket_cursor,
                            BinRec* __restrict__ binned) {
    __shared__ int hcnt[NBUCKET];
    __shared__ int hbase[NBUCKET];
    int tid = threadIdx.x;
    for (int i = tid; i < NBUCKET; i += 256) hcnt[i] = 0;
    __syncthreads();
    int base = blockIdx.x * EPB;
    int end = base + EPB; if (end > N_EDGES) end = N_EDGES;
    for (int e = base + tid; e < end; e += 256)
        atomicAdd(&hcnt[col[e] >> BSHIFT], 1);
    __syncthreads();
    for (int i = tid; i < NBUCKET; i += 256) {
        int c = hcnt[i];
        hbase[i] = c ? atomicAdd(&bucket_cursor[i], c) : 0;
        hcnt[i] = 0;   // reuse as local cursor (same thread owns index i)
    }
    __syncthreads();
    for (int e = base + tid; e < end; e += 256) {
        int c = col[e];
        int b = c >> BSHIFT;
        int rk = atomicAdd(&hcnt[b], 1);
        BinRec r;
        r.meta = (unsigned)row[e] | ((unsigned)(c & (BNODES - 1)) << 20);
        r.ew = ew[e];
        binned[hbase[b] + rk] = r;
    }
}

// Phase D1: per-bucket node counts + float deg (LDS), scan -> start[], dinv[]
__global__ void bucket_stats(const BinRec* __restrict__ binned,
                             const int* __restrict__ bucket_base,
                             const int* __restrict__ bucket_cnt,
                             float* __restrict__ dinv,
                             int* __restrict__ start) {
    __shared__ int   cnt[BNODES];
    __shared__ float deg[BNODES];
    __shared__ int   wsum[2];
    int b = blockIdx.x;
    int tid = threadIdx.x;
    if (tid < BNODES) { cnt[tid] = 0; deg[tid] = 0.0f; }
    __syncthreads();
    int s = bucket_base[b], n = bucket_cnt[b];
    for (int i = tid; i < n; i += 256) {
        BinRec r = binned[s + i];
        int l = r.meta >> 20;
        atomicAdd(&cnt[l], 1);
        atomicAdd(&deg[l], r.ew);
    }
    __syncthreads();
    if (tid < BNODES) {
        int lane = tid & 63, wid = tid >> 6;
        int v = cnt[tid];
        int inc = v;
        #pragma unroll
        for (int o = 1; o < 64; o <<= 1) {
            int u = __shfl_up(inc, o, 64);
            if (lane >= o) inc += u;
        }
        if (lane == 63) wsum[wid] = inc;
        __syncthreads();
        int excl = inc - v + ((wid == 1) ? wsum[0] : 0);
        int node = (b << BSHIFT) + tid;
        if (node < N_NODES) {
            start[node] = s + excl;
            float d = deg[tid];
            dinv[node] = (d > 0.0f) ? rsqrtf(d) : 0.0f;
        }
    }
}

// Phase D2: scatter edges within bucket window -> final rec {src, dinv[src]*ew}
__global__ void bucket_scatter(const BinRec* __restrict__ binned,
                               const int* __restrict__ bucket_base,
                               const int* __restrict__ bucket_cnt,
                               const int* __restrict__ start,
                               const float* __restrict__ dinv,
                               EdgeRec* __restrict__ rec) {
    __shared__ int cur[BNODES];
    int b = blockIdx.x;
    int tid = threadIdx.x;
    if (tid < BNODES) {
        int node = (b << BSHIFT) + tid;
        cur[tid] = (node < N_NODES) ? start[node] : 0;
    }
    __syncthreads();
    int s = bucket_base[b], n = bucket_cnt[b];
    for (int i = tid; i < n; i += 256) {
        BinRec r = binned[s + i];
        int l = r.meta >> 20;
        int src = (int)(r.meta & 0xFFFFFu);
        int pos = atomicAdd(&cur[l], 1);
        EdgeRec o;
        o.s = src;
        o.w = dinv[src] * r.ew;
        rec[pos] = o;
    }
}

// ---------------------------------------------------------------------------
// Degree counting sort: perm orders nodes by degree so co-scheduled 16-lane
// groups have near-equal trip counts.
__global__ void deg_hist(const int* __restrict__ start, int* __restrict__ dhist) {
    __shared__ int h[DBINS];
    int tid = threadIdx.x;
    for (int i = tid; i < DBINS; i += 256) h[i] = 0;
    __syncthreads();
    int base = blockIdx.x * DNPB;
    int end = base + DNPB; if (end > N_NODES) end = N_NODES;
    for (int n = base + tid; n < end; n += 256) {
        int d = start[n + 1] - start[n];
        if (d > DBINS - 1) d = DBINS - 1;
        atomicAdd(&h[d], 1);
    }
    __syncthreads();
    for (int i = tid; i < DBINS; i += 256)
        if (h[i]) atomicAdd(&dhist[i], h[i]);
}

__global__ void deg_scan(const int* __restrict__ dhist, int* __restrict__ dcursor) {
    __shared__ int ws[8];
    int t = threadIdx.x;            // 512 threads
    int lane = t & 63, wid = t >> 6;
    int v = dhist[t];
    int inc = v;
    #pragma unroll
    for (int o = 1; o < 64; o <<= 1) {
        int u = __shfl_up(inc, o, 64);
        if (lane >= o) inc += u;
    }
    if (lane == 63) ws[wid] = inc;
    __syncthreads();
    int woff = 0;
    for (int w = 0; w < wid; ++w) woff += ws[w];
    dcursor[t] = woff + inc - v;   // exclusive
}

__global__ void deg_scatter(const int* __restrict__ start,
                            int* __restrict__ dcursor,
                            int* __restrict__ perm) {
    __shared__ int h[DBINS];
    __shared__ int hb[DBINS];
    int tid = threadIdx.x;
    for (int i = tid; i < DBINS; i += 256) h[i] = 0;
    __syncthreads();
    int base = blockIdx.x * DNPB;
    int end = base + DNPB; if (end > N_NODES) end = N_NODES;
    for (int n = base + tid; n < end; n += 256) {
        int d = start[n + 1] - start[n];
        if (d > DBINS - 1) d = DBINS - 1;
        atomicAdd(&h[d], 1);
    }
    __syncthreads();
    for (int i = tid; i < DBINS; i += 256) {
        int c = h[i];
        hb[i] = c ? atomicAdd(&dcursor[i], c) : 0;
        h[i] = 0;   // reuse as local cursor
    }
    __syncthreads();
    for (int n = base + tid; n < end; n += 256) {
        int d = start[n + 1] - start[n];
        if (d > DBINS - 1) d = DBINS - 1;
        int rk = atomicAdd(&h[d], 1);
        perm[hb[d] + rk] = n;
    }
}

// ---------------------------------------------------------------------------
// 16 lanes per node, 4 dims per lane: xout[n] = bf16(dinv[n] * sum w_j x[src_j])
__global__ void prop16_kernel(const unsigned short* __restrict__ xin,
                              unsigned short* __restrict__ xout,
                              const EdgeRec* __restrict__ rec,
                              const int* __restrict__ start,
                              const float* __restrict__ dinv,
                              const int* __restrict__ perm) {
    int t = blockIdx.x * blockDim.x + threadIdx.x;
    int slot = t >> 4;
    int q = (t & 15) << 2;          // dim offset
    if (slot >= N_NODES) return;
    int n = perm[slot];
    int s = start[n], e = start[n + 1];
    float a0 = 0.f, a1 = 0.f, a2 = 0.f, a3 = 0.f;
    int j = s;
    for (; j + 2 <= e; j += 2) {
        EdgeRec r0 = rec[j], r1 = rec[j + 1];
        ushort4 h0 = *(const ushort4*)(xin + (((size_t)r0.s) << 6) + q);
        ushort4 h1 = *(const ushort4*)(xin + (((size_t)r1.s) << 6) + q);
        a0 += r0.w * bf2f(h0.x) + r1.w * bf2f(h1.x);
        a1 += r0.w * bf2f(h0.y) + r1.w * bf2f(h1.y);
        a2 += r0.w * bf2f(h0.z) + r1.w * bf2f(h1.z);
        a3 += r0.w * bf2f(h0.w) + r1.w * bf2f(h1.w);
    }
    if (j < e) {
        EdgeRec r = rec[j];
        ushort4 h = *(const ushort4*)(xin + (((size_t)r.s) << 6) + q);
        a0 += r.w * bf2f(h.x);
        a1 += r.w * bf2f(h.y);
        a2 += r.w * bf2f(h.z);
        a3 += r.w * bf2f(h.w);
    }
    float dn = dinv[n];
    ushort4 o;
    o.x = f2bf(dn * a0);
    o.y = f2bf(dn * a1);
    o.z = f2bf(dn * a2);
    o.w = f2bf(dn * a3);
    *(ushort4*)(xout + (((size_t)n) << 6) + q) = o;
}

// last propagation fused with weighted layer-combine + row L2-normalize
__global__ void prop16_combine_kernel(const unsigned short* __restrict__ x2h,
                                      const float* __restrict__ x0,
                                      const unsigned short* __restrict__ x1h,
                                      const EdgeRec* __restrict__ rec,
                                      const int* __restrict__ start,
                                      const float* __restrict__ dinv,
                                      const float* __restrict__ lw,
                                      const int* __restrict__ perm,
                                      float* __restrict__ out) {
    int t = blockIdx.x * blockDim.x + threadIdx.x;
    int slot = t >> 4;
    int q = (t & 15) << 2;
    if (slot >= N_NODES) return;
    int n = perm[slot];
    int s = start[n], e = start[n + 1];
    float a0 = 0.f, a1 = 0.f, a2 = 0.f, a3 = 0.f;
    int j = s;
    for (; j + 2 <= e; j += 2) {
        EdgeRec r0 = rec[j], r1 = rec[j + 1];
        ushort4 h0 = *(const ushort4*)(x2h + (((size_t)r0.s) << 6) + q);
        ushort4 h1 = *(const ushort4*)(x2h + (((size_t)r1.s) << 6) + q);
        a0 += r0.w * bf2f(h0.x) + r1.w * bf2f(h1.x);
        a1 += r0.w * bf2f(h0.y) + r1.w * bf2f(h1.y);
        a2 += r0.w * bf2f(h0.z) + r1.w * bf2f(h1.z);
        a3 += r0.w * bf2f(h0.w) + r1.w * bf2f(h1.w);
    }
    if (j < e) {
        EdgeRec r = rec[j];
        ushort4 h = *(const ushort4*)(x2h + (((size_t)r.s) << 6) + q);
        a0 += r.w * bf2f(h.x);
        a1 += r.w * bf2f(h.y);
        a2 += r.w * bf2f(h.z);
        a3 += r.w * bf2f(h.w);
    }
    float dn = dinv[n];
    float x3v0 = dn * a0, x3v1 = dn * a1, x3v2 = dn * a2, x3v3 = dn * a3;

    float w0 = lw[0], w1 = lw[1], w2 = lw[2], w3 = lw[3];
    float m = fmaxf(fmaxf(w0, w1), fmaxf(w2, w3));
    float e0 = expf(w0 - m), e1 = expf(w1 - m), e2 = expf(w2 - m), e3 = expf(w3 - m);
    float inv_s = 1.0f / (e0 + e1 + e2 + e3);

    size_t off = (((size_t)n) << 6) + q;
    float4 xv = *(const float4*)(x0 + off);
    ushort4 h1v = *(const ushort4*)(x1h + off);
    ushort4 h2v = *(const ushort4*)(x2h + off);

    float v0 = (e0 * xv.x + e1 * bf2f(h1v.x) + e2 * bf2f(h2v.x) + e3 * x3v0) * inv_s;
    float v1 = (e0 * xv.y + e1 * bf2f(h1v.y) + e2 * bf2f(h2v.y) + e3 * x3v1) * inv_s;
    float v2 = (e0 * xv.z + e1 * bf2f(h1v.z) + e2 * bf2f(h2v.z) + e3 * x3v2) * inv_s;
    float v3 = (e0 * xv.w + e1 * bf2f(h1v.w) + e2 * bf2f(h2v.w) + e3 * x3v3) * inv_s;

    float sq = v0 * v0 + v1 * v1 + v2 * v2 + v3 * v3;
    #pragma unroll
    for (int o = 1; o < 16; o <<= 1) sq += __shfl_xor(sq, o, 64);  // within 16-lane group
    float nrm = fmaxf(sqrtf(sq), 1e-12f);
    float inv_n = 1.0f / nrm;

    float4 ov;
    ov.x = v0 * inv_n; ov.y = v1 * inv_n; ov.z = v2 * inv_n; ov.w = v3 * inv_n;
    *(float4*)(out + off) = ov;
}

// ---------------------------------------------------------------------------
extern "C" void kernel_launch(void* const* d_in, const int* in_sizes, int n_in,
                              void* d_out, int out_size, void* d_ws, size_t ws_size,
                              hipStream_t stream) {
    const float* emb = (const float*)d_in[0];   // [N, 64]
    const float* lw  = (const float*)d_in[1];   // [4]
    const float* ew  = (const float*)d_in[2];   // [E]
    const int*   ei  = (const int*)d_in[3];     // [2, E]
    const int* row = ei;                        // sources
    const int* col = ei + N_EDGES;              // targets
    float* out = (float*)d_out;

    // workspace layout (8B-aligned pieces)
    char* p = (char*)d_ws;
    BinRec*  binned = (BinRec*)p;               p += (size_t)N_EDGES * sizeof(BinRec);  // 9.6 MB
    EdgeRec* rec    = (EdgeRec*)p;              p += (size_t)N_EDGES * sizeof(EdgeRec); // 9.6 MB
    unsigned short* embh = (unsigned short*)p;  p += (size_t)N_NODES * EMB_DIM * 2;     // 12.8 MB
    unsigned short* x1h  = (unsigned short*)p;  p += (size_t)N_NODES * EMB_DIM * 2;     // 12.8 MB
    unsigned short* x2h  = (unsigned short*)p;  p += (size_t)N_NODES * EMB_DIM * 2;     // 12.8 MB
    float* dinv  = (float*)p;                   p += (size_t)N_NODES * 4;
    int*   startA= (int*)p;                     p += (size_t)(N_NODES + 8) * 4;
    int*   perm  = (int*)p;                     p += (size_t)N_NODES * 4;
    int*   bucket_cnt    = (int*)p;             p += (size_t)NBUCKET * 4;
    int*   bucket_base   = (int*)p;             p += (size_t)NBUCKET * 4;
    int*   bucket_cursor = (int*)p;             p += (size_t)NBUCKET * 4;
    int*   dhist   = (int*)p;                   p += (size_t)DBINS * 4;
    int*   dcursor = (int*)p;                   p += (size_t)DBINS * 4;

    hipMemsetAsync(bucket_cnt, 0, NBUCKET * sizeof(int), stream);
    hipMemsetAsync(dhist, 0, DBINS * sizeof(int), stream);

    const int B = 256;

    cvt_emb<<<(N_NODES * EMB_DIM / 8 + B - 1) / B, B, 0, stream>>>(emb, embh);
    bin_hist<<<NBLK_BIN, B, 0, stream>>>(col, bucket_cnt);
    bucket_scan<<<1, 1024, 0, stream>>>(bucket_cnt, bucket_base, bucket_cursor, startA);
    bin_scatter<<<NBLK_BIN, B, 0, stream>>>(row, col, ew, bucket_cursor, binned);
    bucket_stats<<<NBUCKET, B, 0, stream>>>(binned, bucket_base, bucket_cnt, dinv, startA);
    bucket_scatter<<<NBUCKET, B, 0, stream>>>(binned, bucket_base, bucket_cnt, startA, dinv, rec);
    deg_hist<<<NBLK_DEG, B, 0, stream>>>(startA, dhist);
    deg_scan<<<1, DBINS, 0, stream>>>(dhist, dcursor);
    deg_scatter<<<NBLK_DEG, B, 0, stream>>>(startA, dcursor, perm);

    long pt = (long)N_NODES * 16;   // 16 lanes per node
    int pgrid = (int)((pt + B - 1) / B);
    prop16_kernel<<<pgrid, B, 0, stream>>>(embh, x1h, rec, startA, dinv, perm);
    prop16_kernel<<<pgrid, B, 0, stream>>>(x1h, x2h, rec, startA, dinv, perm);
    prop16_combine_kernel<<<pgrid, B, 0, stream>>>(x2h, emb, x1h, rec, startA, dinv, lw, perm, out);
}

// Round 8
// 168.886 us; speedup vs baseline: 5.3552x; 1.1836x over previous
//
#include <hip/hip_runtime.h>

#define N_NODES 100000
#define EMB_DIM 64
#define N_EDGES 1200000

#define BSHIFT  7
#define BNODES  128
#define NBUCKET ((N_NODES + BNODES - 1) / BNODES)   // 782
#define CAP     2048                                 // padded bucket capacity
#define EPB     4096                                 // edges per binning block
#define NBLK_BIN ((N_EDGES + EPB - 1) / EPB)         // 293

#define DBINS 512
#define DNPB  1024
#define NBLK_DEG ((N_NODES + DNPB - 1) / DNPB)       // 98

struct __align__(8) EdgeRec {
    int   s;   // source node
    float w;   // edge_weight (y-space: no dinv folded in)
};

struct __align__(8) BinRec {
    unsigned meta;  // src (bits 0..19) | local_dst (bits 20..26)
    float    ew;
};

// bf16 helpers (RNE)
__device__ __forceinline__ unsigned short f2bf(float f) {
    unsigned u = __float_as_uint(f);
    u += 0x7FFFu + ((u >> 16) & 1u);
    return (unsigned short)(u >> 16);
}
__device__ __forceinline__ float bf2f(unsigned short h) {
    return __uint_as_float((unsigned)h << 16);
}

// ---------------------------------------------------------------------------
__global__ void init_kernel(int* __restrict__ bucket_cursor, int* __restrict__ dhist) {
    int t = threadIdx.x;   // 1024
    if (t < NBUCKET) bucket_cursor[t] = t * CAP;
    if (t < DBINS)   dhist[t] = 0;
}

// One-pass binning into padded per-bucket windows (direct reservation).
__global__ void bin_scatter(const int* __restrict__ row,
                            const int* __restrict__ col,
                            const float* __restrict__ ew,
                            int* __restrict__ bucket_cursor,
                            BinRec* __restrict__ binned) {
    __shared__ int hcnt[NBUCKET];
    __shared__ int hbase[NBUCKET];
    int tid = threadIdx.x;   // 1024
    if (tid < NBUCKET) hcnt[tid] = 0;
    __syncthreads();
    int base = blockIdx.x * EPB;
    int end = base + EPB; if (end > N_EDGES) end = N_EDGES;
    for (int e = base + tid; e < end; e += 1024)
        atomicAdd(&hcnt[col[e] >> BSHIFT], 1);
    __syncthreads();
    if (tid < NBUCKET) {
        int c = hcnt[tid];
        hbase[tid] = c ? atomicAdd(&bucket_cursor[tid], c) : 0;
        hcnt[tid] = 0;   // reuse as local cursor
    }
    __syncthreads();
    for (int e = base + tid; e < end; e += 1024) {
        int c = col[e];
        int b = c >> BSHIFT;
        int rk = atomicAdd(&hcnt[b], 1);
        BinRec r;
        r.meta = (unsigned)row[e] | ((unsigned)(c & (BNODES - 1)) << 20);
        r.ew = ew[e];
        binned[hbase[b] + rk] = r;
    }
}

// Exclusive scan of bucket counts (derived from cursors) -> CSR bases
__global__ void bucket_scan(const int* __restrict__ cursor,
                            int* __restrict__ csr_base,
                            int* __restrict__ start) {
    __shared__ int ws[16];
    int t = threadIdx.x;            // 1024 threads
    int lane = t & 63, wid = t >> 6;
    int v = (t < NBUCKET) ? (cursor[t] - t * CAP) : 0;
    int inc = v;
    #pragma unroll
    for (int o = 1; o < 64; o <<= 1) {
        int u = __shfl_up(inc, o, 64);
        if (lane >= o) inc += u;
    }
    if (lane == 63) ws[wid] = inc;
    __syncthreads();
    int woff = 0;
    for (int w = 0; w < wid; ++w) woff += ws[w];
    if (t < NBUCKET) csr_base[t] = woff + inc - v;
    if (t == 0) start[N_NODES] = N_EDGES;
}

// Merged stats+scatter: per-bucket node counts/deg (LDS), local scan ->
// start[], dinv[], rdinv[]; then scatter {src, ew} into CSR rec[].
__global__ void bucket_build(const BinRec* __restrict__ binned,
                             const int* __restrict__ cursor,
                             const int* __restrict__ csr_base,
                             float* __restrict__ dinv,
                             float* __restrict__ rdinv,
                             int* __restrict__ start,
                             EdgeRec* __restrict__ rec) {
    __shared__ int   cnt[BNODES];
    __shared__ float deg[BNODES];
    __shared__ int   cur[BNODES];
    __shared__ int   wsum[2];
    int b = blockIdx.x;
    int tid = threadIdx.x;   // 256
    if (tid < BNODES) { cnt[tid] = 0; deg[tid] = 0.0f; }
    __syncthreads();
    int s = b * CAP;
    int n = cursor[b] - s;
    for (int i = tid; i < n; i += 256) {
        BinRec r = binned[s + i];
        int l = r.meta >> 20;
        atomicAdd(&cnt[l], 1);
        atomicAdd(&deg[l], r.ew);
    }
    __syncthreads();
    int lane = tid & 63, wid = tid >> 6;
    int v = (tid < BNODES) ? cnt[tid] : 0;
    int inc = v;
    #pragma unroll
    for (int o = 1; o < 64; o <<= 1) {
        int u = __shfl_up(inc, o, 64);
        if (lane >= o) inc += u;
    }
    if (tid < BNODES && lane == 63) wsum[wid] = inc;
    __syncthreads();
    if (tid < BNODES) {
        int excl = inc - v + ((wid == 1) ? wsum[0] : 0);
        int node = (b << BSHIFT) + tid;
        if (node < N_NODES) {
            int st = csr_base[b] + excl;
            start[node] = st;
            cur[tid] = st;
            float d = deg[tid];
            dinv[node]  = (d > 0.0f) ? rsqrtf(d) : 0.0f;
            rdinv[node] = (d > 0.0f) ? sqrtf(d)  : 0.0f;
        } else {
            cur[tid] = 0;
        }
    }
    __syncthreads();
    for (int i = tid; i < n; i += 256) {
        BinRec r = binned[s + i];
        int l = r.meta >> 20;
        int pos = atomicAdd(&cur[l], 1);
        EdgeRec o;
        o.s = (int)(r.meta & 0xFFFFFu);
        o.w = r.ew;
        rec[pos] = o;
    }
}

// y0[n][d] = bf16(dinv[n] * emb[n][d])
__global__ void cvt_y0(const float* __restrict__ emb,
                       const float* __restrict__ dinv,
                       unsigned short* __restrict__ y0) {
    int t = blockIdx.x * blockDim.x + threadIdx.x;
    long base = (long)t * 8;
    if (base + 8 <= (long)N_NODES * EMB_DIM) {
        float dn = dinv[t >> 3];
        float4 a = *(const float4*)(emb + base);
        float4 b = *(const float4*)(emb + base + 4);
        uint4 o;
        o.x = (unsigned)f2bf(dn * a.x) | ((unsigned)f2bf(dn * a.y) << 16);
        o.y = (unsigned)f2bf(dn * a.z) | ((unsigned)f2bf(dn * a.w) << 16);
        o.z = (unsigned)f2bf(dn * b.x) | ((unsigned)f2bf(dn * b.y) << 16);
        o.w = (unsigned)f2bf(dn * b.z) | ((unsigned)f2bf(dn * b.w) << 16);
        *(uint4*)(y0 + base) = o;
    }
}

// ---------------------------------------------------------------------------
// Degree counting sort: perm orders nodes by degree so co-scheduled 16-lane
// groups have near-equal trip counts.
__global__ void deg_hist(const int* __restrict__ start, int* __restrict__ dhist) {
    __shared__ int h[DBINS];
    int tid = threadIdx.x;
    for (int i = tid; i < DBINS; i += 256) h[i] = 0;
    __syncthreads();
    int base = blockIdx.x * DNPB;
    int end = base + DNPB; if (end > N_NODES) end = N_NODES;
    for (int n = base + tid; n < end; n += 256) {
        int d = start[n + 1] - start[n];
        if (d > DBINS - 1) d = DBINS - 1;
        atomicAdd(&h[d], 1);
    }
    __syncthreads();
    for (int i = tid; i < DBINS; i += 256)
        if (h[i]) atomicAdd(&dhist[i], h[i]);
}

__global__ void deg_scan(const int* __restrict__ dhist, int* __restrict__ dcursor) {
    __shared__ int ws[8];
    int t = threadIdx.x;            // 512 threads
    int lane = t & 63, wid = t >> 6;
    int v = dhist[t];
    int inc = v;
    #pragma unroll
    for (int o = 1; o < 64; o <<= 1) {
        int u = __shfl_up(inc, o, 64);
        if (lane >= o) inc += u;
    }
    if (lane == 63) ws[wid] = inc;
    __syncthreads();
    int woff = 0;
    for (int w = 0; w < wid; ++w) woff += ws[w];
    dcursor[t] = woff + inc - v;   // exclusive
}

__global__ void deg_scatter(const int* __restrict__ start,
                            int* __restrict__ dcursor,
                            int* __restrict__ perm) {
    __shared__ int h[DBINS];
    __shared__ int hb[DBINS];
    int tid = threadIdx.x;
    for (int i = tid; i < DBINS; i += 256) h[i] = 0;
    __syncthreads();
    int base = blockIdx.x * DNPB;
    int end = base + DNPB; if (end > N_NODES) end = N_NODES;
    for (int n = base + tid; n < end; n += 256) {
        int d = start[n + 1] - start[n];
        if (d > DBINS - 1) d = DBINS - 1;
        atomicAdd(&h[d], 1);
    }
    __syncthreads();
    for (int i = tid; i < DBINS; i += 256) {
        int c = h[i];
        hb[i] = c ? atomicAdd(&dcursor[i], c) : 0;
        h[i] = 0;   // reuse as local cursor
    }
    __syncthreads();
    for (int n = base + tid; n < end; n += 256) {
        int d = start[n + 1] - start[n];
        if (d > DBINS - 1) d = DBINS - 1;
        int rk = atomicAdd(&h[d], 1);
        perm[hb[d] + rk] = n;
    }
}

// ---------------------------------------------------------------------------
// 16 lanes per node, 4 dims per lane: yout[n] = bf16(dinv[n]^2 * sum ew_j y[src_j])
__global__ void prop16_kernel(const unsigned short* __restrict__ yin,
                              unsigned short* __restrict__ yout,
                              const EdgeRec* __restrict__ rec,
                              const int* __restrict__ start,
                              const float* __restrict__ dinv,
                              const int* __restrict__ perm) {
    int t = blockIdx.x * blockDim.x + threadIdx.x;
    int slot = t >> 4;
    int q = (t & 15) << 2;          // dim offset
    if (slot >= N_NODES) return;
    int n = perm[slot];
    int s = start[n], e = start[n + 1];
    float a0 = 0.f, a1 = 0.f, a2 = 0.f, a3 = 0.f;
    int j = s;
    for (; j + 2 <= e; j += 2) {
        EdgeRec r0 = rec[j], r1 = rec[j + 1];
        ushort4 h0 = *(const ushort4*)(yin + (((size_t)r0.s) << 6) + q);
        ushort4 h1 = *(const ushort4*)(yin + (((size_t)r1.s) << 6) + q);
        a0 += r0.w * bf2f(h0.x) + r1.w * bf2f(h1.x);
        a1 += r0.w * bf2f(h0.y) + r1.w * bf2f(h1.y);
        a2 += r0.w * bf2f(h0.z) + r1.w * bf2f(h1.z);
        a3 += r0.w * bf2f(h0.w) + r1.w * bf2f(h1.w);
    }
    if (j < e) {
        EdgeRec r = rec[j];
        ushort4 h = *(const ushort4*)(yin + (((size_t)r.s) << 6) + q);
        a0 += r.w * bf2f(h.x);
        a1 += r.w * bf2f(h.y);
        a2 += r.w * bf2f(h.z);
        a3 += r.w * bf2f(h.w);
    }
    float dn = dinv[n];
    float dn2 = dn * dn;
    ushort4 o;
    o.x = f2bf(dn2 * a0);
    o.y = f2bf(dn2 * a1);
    o.z = f2bf(dn2 * a2);
    o.w = f2bf(dn2 * a3);
    *(ushort4*)(yout + (((size_t)n) << 6) + q) = o;
}

// last propagation fused with weighted layer-combine + row L2-normalize
// x_l = y_l * rdinv[n]; x3 = dinv[n] * sum ew y2[src]
__global__ void prop16_combine_kernel(const unsigned short* __restrict__ y2h,
                                      const float* __restrict__ x0,
                                      const unsigned short* __restrict__ y1h,
                                      const EdgeRec* __restrict__ rec,
                                      const int* __restrict__ start,
                                      const float* __restrict__ dinv,
                                      const float* __restrict__ rdinv,
                                      const float* __restrict__ lw,
                                      const int* __restrict__ perm,
                                      float* __restrict__ out) {
    int t = blockIdx.x * blockDim.x + threadIdx.x;
    int slot = t >> 4;
    int q = (t & 15) << 2;
    if (slot >= N_NODES) return;
    int n = perm[slot];
    int s = start[n], e = start[n + 1];
    float a0 = 0.f, a1 = 0.f, a2 = 0.f, a3 = 0.f;
    int j = s;
    for (; j + 2 <= e; j += 2) {
        EdgeRec r0 = rec[j], r1 = rec[j + 1];
        ushort4 h0 = *(const ushort4*)(y2h + (((size_t)r0.s) << 6) + q);
        ushort4 h1 = *(const ushort4*)(y2h + (((size_t)r1.s) << 6) + q);
        a0 += r0.w * bf2f(h0.x) + r1.w * bf2f(h1.x);
        a1 += r0.w * bf2f(h0.y) + r1.w * bf2f(h1.y);
        a2 += r0.w * bf2f(h0.z) + r1.w * bf2f(h1.z);
        a3 += r0.w * bf2f(h0.w) + r1.w * bf2f(h1.w);
    }
    if (j < e) {
        EdgeRec r = rec[j];
        ushort4 h = *(const ushort4*)(y2h + (((size_t)r.s) << 6) + q);
        a0 += r.w * bf2f(h.x);
        a1 += r.w * bf2f(h.y);
        a2 += r.w * bf2f(h.z);
        a3 += r.w * bf2f(h.w);
    }
    float dn = dinv[n];
    float rn = rdinv[n];
    float x3v0 = dn * a0, x3v1 = dn * a1, x3v2 = dn * a2, x3v3 = dn * a3;

    float w0 = lw[0], w1 = lw[1], w2 = lw[2], w3 = lw[3];
    float m = fmaxf(fmaxf(w0, w1), fmaxf(w2, w3));
    float e0 = expf(w0 - m), e1 = expf(w1 - m), e2 = expf(w2 - m), e3 = expf(w3 - m);
    float inv_s = 1.0f / (e0 + e1 + e2 + e3);

    size_t off = (((size_t)n) << 6) + q;
    float4 xv = *(const float4*)(x0 + off);
    ushort4 h1v = *(const ushort4*)(y1h + off);
    ushort4 h2v = *(const ushort4*)(y2h + off);

    float v0 = (e0 * xv.x + e1 * bf2f(h1v.x) * rn + e2 * bf2f(h2v.x) * rn + e3 * x3v0) * inv_s;
    float v1 = (e0 * xv.y + e1 * bf2f(h1v.y) * rn + e2 * bf2f(h2v.y) * rn + e3 * x3v1) * inv_s;
    float v2 = (e0 * xv.z + e1 * bf2f(h1v.z) * rn + e2 * bf2f(h2v.z) * rn + e3 * x3v2) * inv_s;
    float v3 = (e0 * xv.w + e1 * bf2f(h1v.w) * rn + e2 * bf2f(h2v.w) * rn + e3 * x3v3) * inv_s;

    float sq = v0 * v0 + v1 * v1 + v2 * v2 + v3 * v3;
    #pragma unroll
    for (int o = 1; o < 16; o <<= 1) sq += __shfl_xor(sq, o, 64);  // within 16-lane group
    float nrm = fmaxf(sqrtf(sq), 1e-12f);
    float inv_n = 1.0f / nrm;

    float4 ov;
    ov.x = v0 * inv_n; ov.y = v1 * inv_n; ov.z = v2 * inv_n; ov.w = v3 * inv_n;
    *(float4*)(out + off) = ov;
}

// ---------------------------------------------------------------------------
extern "C" void kernel_launch(void* const* d_in, const int* in_sizes, int n_in,
                              void* d_out, int out_size, void* d_ws, size_t ws_size,
                              hipStream_t stream) {
    const float* emb = (const float*)d_in[0];   // [N, 64]
    const float* lw  = (const float*)d_in[1];   // [4]
    const float* ew  = (const float*)d_in[2];   // [E]
    const int*   ei  = (const int*)d_in[3];     // [2, E]
    const int* row = ei;                        // sources
    const int* col = ei + N_EDGES;              // targets
    float* out = (float*)d_out;

    // workspace layout (8B-aligned pieces)
    char* p = (char*)d_ws;
    BinRec*  binned = (BinRec*)p;               p += (size_t)NBUCKET * CAP * sizeof(BinRec); // 12.8 MB
    EdgeRec* rec    = (EdgeRec*)p;              p += (size_t)N_EDGES * sizeof(EdgeRec);      // 9.6 MB
    unsigned short* y0h = (unsigned short*)p;   p += (size_t)N_NODES * EMB_DIM * 2;          // 12.8 MB
    unsigned short* y1h = (unsigned short*)p;   p += (size_t)N_NODES * EMB_DIM * 2;          // 12.8 MB
    unsigned short* y2h = (unsigned short*)p;   p += (size_t)N_NODES * EMB_DIM * 2;          // 12.8 MB
    float* dinv  = (float*)p;                   p += (size_t)N_NODES * 4;
    float* rdinv = (float*)p;                   p += (size_t)N_NODES * 4;
    int*   startA= (int*)p;                     p += (size_t)(N_NODES + 8) * 4;
    int*   perm  = (int*)p;                     p += (size_t)N_NODES * 4;
    int*   csr_base      = (int*)p;             p += (size_t)NBUCKET * 4;
    int*   bucket_cursor = (int*)p;             p += (size_t)NBUCKET * 4;
    int*   dhist   = (int*)p;                   p += (size_t)DBINS * 4;
    int*   dcursor = (int*)p;                   p += (size_t)DBINS * 4;

    const int B = 256;

    init_kernel<<<1, 1024, 0, stream>>>(bucket_cursor, dhist);
    bin_scatter<<<NBLK_BIN, 1024, 0, stream>>>(row, col, ew, bucket_cursor, binned);
    bucket_scan<<<1, 1024, 0, stream>>>(bucket_cursor, csr_base, startA);
    bucket_build<<<NBUCKET, B, 0, stream>>>(binned, bucket_cursor, csr_base,
                                            dinv, rdinv, startA, rec);
    cvt_y0<<<(N_NODES * EMB_DIM / 8 + B - 1) / B, B, 0, stream>>>(emb, dinv, y0h);
    deg_hist<<<NBLK_DEG, B, 0, stream>>>(startA, dhist);
    deg_scan<<<1, DBINS, 0, stream>>>(dhist, dcursor);
    deg_scatter<<<NBLK_DEG, B, 0, stream>>>(startA, dcursor, perm);

    long pt = (long)N_NODES * 16;   // 16 lanes per node
    int pgrid = (int)((pt + B - 1) / B);
    prop16_kernel<<<pgrid, B, 0, stream>>>(y0h, y1h, rec, startA, dinv, perm);
    prop16_kernel<<<pgrid, B, 0, stream>>>(y1h, y2h, rec, startA, dinv, perm);
    prop16_combine_kernel<<<pgrid, B, 0, stream>>>(y2h, emb, y1h, rec, startA, dinv,
                                                   rdinv, lw, perm, out);
}

// Round 9
// 157.096 us; speedup vs baseline: 5.7572x; 1.0751x over previous
//
#include <hip/hip_runtime.h>

#define N_NODES 100000
#define EMB_DIM 64
#define N_EDGES 1200000

#define BSHIFT  7
#define BNODES  128
#define NBUCKET ((N_NODES + BNODES - 1) / BNODES)   // 782
#define CAP     2048                                 // padded bucket capacity
#define EPB     4096                                 // edges per binning block
#define NBLK_BIN ((N_EDGES + EPB - 1) / EPB)         // 293

#define DBINS 512
#define DNPB  1024
#define NBLK_DEG ((N_NODES + DNPB - 1) / DNPB)       // 98

typedef unsigned short ushort8v __attribute__((ext_vector_type(8)));

struct __align__(8) EdgeRec {
    int   s;   // source node
    float w;   // edge_weight (y-space: no dinv folded in)
};

struct __align__(8) BinRec {
    unsigned meta;  // src (bits 0..19) | local_dst (bits 20..26)
    float    ew;
};

// bf16 helpers (RNE)
__device__ __forceinline__ unsigned short f2bf(float f) {
    unsigned u = __float_as_uint(f);
    u += 0x7FFFu + ((u >> 16) & 1u);
    return (unsigned short)(u >> 16);
}
__device__ __forceinline__ float bf2f(unsigned short h) {
    return __uint_as_float((unsigned)h << 16);
}

// ---------------------------------------------------------------------------
__global__ void init_kernel(int* __restrict__ bucket_cursor, int* __restrict__ dhist) {
    int t = threadIdx.x;   // 1024
    if (t < NBUCKET) bucket_cursor[t] = t * CAP;
    if (t < DBINS)   dhist[t] = 0;
}

// One-pass binning into padded per-bucket windows (direct reservation).
__global__ void bin_scatter(const int* __restrict__ row,
                            const int* __restrict__ col,
                            const float* __restrict__ ew,
                            int* __restrict__ bucket_cursor,
                            BinRec* __restrict__ binned) {
    __shared__ int hcnt[NBUCKET];
    __shared__ int hbase[NBUCKET];
    int tid = threadIdx.x;   // 1024
    if (tid < NBUCKET) hcnt[tid] = 0;
    __syncthreads();
    int base = blockIdx.x * EPB;
    int end = base + EPB; if (end > N_EDGES) end = N_EDGES;
    for (int e = base + tid; e < end; e += 1024)
        atomicAdd(&hcnt[col[e] >> BSHIFT], 1);
    __syncthreads();
    if (tid < NBUCKET) {
        int c = hcnt[tid];
        hbase[tid] = c ? atomicAdd(&bucket_cursor[tid], c) : 0;
        hcnt[tid] = 0;   // reuse as local cursor
    }
    __syncthreads();
    for (int e = base + tid; e < end; e += 1024) {
        int c = col[e];
        int b = c >> BSHIFT;
        int rk = atomicAdd(&hcnt[b], 1);
        BinRec r;
        r.meta = (unsigned)row[e] | ((unsigned)(c & (BNODES - 1)) << 20);
        r.ew = ew[e];
        binned[hbase[b] + rk] = r;
    }
}

// Exclusive scan of bucket counts (derived from cursors) -> CSR bases
__global__ void bucket_scan(const int* __restrict__ cursor,
                            int* __restrict__ csr_base,
                            int* __restrict__ start) {
    __shared__ int ws[16];
    int t = threadIdx.x;            // 1024 threads
    int lane = t & 63, wid = t >> 6;
    int v = (t < NBUCKET) ? (cursor[t] - t * CAP) : 0;
    int inc = v;
    #pragma unroll
    for (int o = 1; o < 64; o <<= 1) {
        int u = __shfl_up(inc, o, 64);
        if (lane >= o) inc += u;
    }
    if (lane == 63) ws[wid] = inc;
    __syncthreads();
    int woff = 0;
    for (int w = 0; w < wid; ++w) woff += ws[w];
    if (t < NBUCKET) csr_base[t] = woff + inc - v;
    if (t == 0) start[N_NODES] = N_EDGES;
}

// Merged stats+scatter+cvt: per-bucket node counts/deg (LDS), local scan ->
// start[], dinv[], rdinv[]; scatter {src, ew} into CSR rec[]; convert this
// bucket's emb rows -> y0 bf16 scaled by dinv; LDS-privatized deg histogram.
__global__ void bucket_build(const BinRec* __restrict__ binned,
                             const int* __restrict__ cursor,
                             const int* __restrict__ csr_base,
                             const float* __restrict__ emb,
                             float* __restrict__ dinv,
                             float* __restrict__ rdinv,
                             int* __restrict__ start,
                             EdgeRec* __restrict__ rec,
                             unsigned short* __restrict__ y0,
                             int* __restrict__ dhist) {
    __shared__ int   cnt[BNODES];
    __shared__ float deg[BNODES];
    __shared__ int   cur[BNODES];
    __shared__ int   dh[DBINS];
    __shared__ int   wsum[2];
    int b = blockIdx.x;
    int tid = threadIdx.x;   // 256
    if (tid < BNODES) { cnt[tid] = 0; deg[tid] = 0.0f; }
    for (int i = tid; i < DBINS; i += 256) dh[i] = 0;
    __syncthreads();
    int s = b * CAP;
    int n = cursor[b] - s;
    for (int i = tid; i < n; i += 256) {
        BinRec r = binned[s + i];
        int l = r.meta >> 20;
        atomicAdd(&cnt[l], 1);
        atomicAdd(&deg[l], r.ew);
    }
    __syncthreads();
    int lane = tid & 63, wid = tid >> 6;
    int v = (tid < BNODES) ? cnt[tid] : 0;
    int inc = v;
    #pragma unroll
    for (int o = 1; o < 64; o <<= 1) {
        int u = __shfl_up(inc, o, 64);
        if (lane >= o) inc += u;
    }
    if (tid < BNODES && lane == 63) wsum[wid] = inc;
    __syncthreads();
    if (tid < BNODES) {
        int excl = inc - v + ((wid == 1) ? wsum[0] : 0);
        int node = (b << BSHIFT) + tid;
        if (node < N_NODES) {
            int st = csr_base[b] + excl;
            start[node] = st;
            cur[tid] = st;
            float d = deg[tid];
            dinv[node]  = (d > 0.0f) ? rsqrtf(d) : 0.0f;
            rdinv[node] = (d > 0.0f) ? sqrtf(d)  : 0.0f;
            int dd = v; if (dd > DBINS - 1) dd = DBINS - 1;
            atomicAdd(&dh[dd], 1);
        } else {
            cur[tid] = 0;
        }
    }
    __syncthreads();
    // scatter into CSR
    for (int i = tid; i < n; i += 256) {
        BinRec r = binned[s + i];
        int l = r.meta >> 20;
        int pos = atomicAdd(&cur[l], 1);
        EdgeRec o;
        o.s = (int)(r.meta & 0xFFFFFu);
        o.w = r.ew;
        rec[pos] = o;
    }
    // flush degree histogram
    for (int i = tid; i < DBINS; i += 256)
        if (dh[i]) atomicAdd(&dhist[i], dh[i]);
    // convert bucket's emb rows -> y0 (bf16, scaled by dinv); 8 elems/thread/pass
    #pragma unroll
    for (int pass = 0; pass < 4; ++pass) {
        int g = (pass * 256 + tid) * 8;    // elem index within bucket [0, 8192)
        int l = g >> 6;
        int node = (b << BSHIFT) + l;
        if (node < N_NODES) {
            float d = deg[l];
            float dn = (d > 0.0f) ? rsqrtf(d) : 0.0f;
            size_t off = (((size_t)node) << 6) + (g & 63);
            float4 a = *(const float4*)(emb + off);
            float4 bb = *(const float4*)(emb + off + 4);
            uint4 o;
            o.x = (unsigned)f2bf(dn * a.x)  | ((unsigned)f2bf(dn * a.y)  << 16);
            o.y = (unsigned)f2bf(dn * a.z)  | ((unsigned)f2bf(dn * a.w)  << 16);
            o.z = (unsigned)f2bf(dn * bb.x) | ((unsigned)f2bf(dn * bb.y) << 16);
            o.w = (unsigned)f2bf(dn * bb.z) | ((unsigned)f2bf(dn * bb.w) << 16);
            *(uint4*)(y0 + off) = o;
        }
    }
}

// ---------------------------------------------------------------------------
__global__ void deg_scan(const int* __restrict__ dhist, int* __restrict__ dcursor) {
    __shared__ int ws[8];
    int t = threadIdx.x;            // 512 threads
    int lane = t & 63, wid = t >> 6;
    int v = dhist[t];
    int inc = v;
    #pragma unroll
    for (int o = 1; o < 64; o <<= 1) {
        int u = __shfl_up(inc, o, 64);
        if (lane >= o) inc += u;
    }
    if (lane == 63) ws[wid] = inc;
    __syncthreads();
    int woff = 0;
    for (int w = 0; w < wid; ++w) woff += ws[w];
    dcursor[t] = woff + inc - v;   // exclusive
}

__global__ void deg_scatter(const int* __restrict__ start,
                            int* __restrict__ dcursor,
                            int* __restrict__ perm) {
    __shared__ int h[DBINS];
    __shared__ int hb[DBINS];
    int tid = threadIdx.x;
    for (int i = tid; i < DBINS; i += 256) h[i] = 0;
    __syncthreads();
    int base = blockIdx.x * DNPB;
    int end = base + DNPB; if (end > N_NODES) end = N_NODES;
    for (int n = base + tid; n < end; n += 256) {
        int d = start[n + 1] - start[n];
        if (d > DBINS - 1) d = DBINS - 1;
        atomicAdd(&h[d], 1);
    }
    __syncthreads();
    for (int i = tid; i < DBINS; i += 256) {
        int c = h[i];
        hb[i] = c ? atomicAdd(&dcursor[i], c) : 0;
        h[i] = 0;   // reuse as local cursor
    }
    __syncthreads();
    for (int n = base + tid; n < end; n += 256) {
        int d = start[n + 1] - start[n];
        if (d > DBINS - 1) d = DBINS - 1;
        int rk = atomicAdd(&h[d], 1);
        perm[hb[d] + rk] = n;
    }
}

// ---------------------------------------------------------------------------
// 8 lanes per node, 8 dims per lane: yout[n] = bf16(dinv[n]^2 * sum ew_j y[src_j])
__global__ void prop8_kernel(const unsigned short* __restrict__ yin,
                             unsigned short* __restrict__ yout,
                             const EdgeRec* __restrict__ rec,
                             const int* __restrict__ start,
                             const float* __restrict__ dinv,
                             const int* __restrict__ perm) {
    int t = blockIdx.x * blockDim.x + threadIdx.x;
    int slot = t >> 3;
    int q = (t & 7) << 3;          // dim offset, 8 dims per lane
    if (slot >= N_NODES) return;
    int n = perm[slot];
    int s = start[n], e = start[n + 1];
    float a0 = 0.f, a1 = 0.f, a2 = 0.f, a3 = 0.f;
    float a4 = 0.f, a5 = 0.f, a6 = 0.f, a7 = 0.f;
    int j = s;
    for (; j + 4 <= e; j += 4) {
        EdgeRec r0 = rec[j], r1 = rec[j + 1], r2 = rec[j + 2], r3 = rec[j + 3];
        ushort8v h0 = *(const ushort8v*)(yin + (((size_t)r0.s) << 6) + q);
        ushort8v h1 = *(const ushort8v*)(yin + (((size_t)r1.s) << 6) + q);
        ushort8v h2 = *(const ushort8v*)(yin + (((size_t)r2.s) << 6) + q);
        ushort8v h3 = *(const ushort8v*)(yin + (((size_t)r3.s) << 6) + q);
        a0 += r0.w * bf2f(h0[0]) + r1.w * bf2f(h1[0]) + r2.w * bf2f(h2[0]) + r3.w * bf2f(h3[0]);
        a1 += r0.w * bf2f(h0[1]) + r1.w * bf2f(h1[1]) + r2.w * bf2f(h2[1]) + r3.w * bf2f(h3[1]);
        a2 += r0.w * bf2f(h0[2]) + r1.w * bf2f(h1[2]) + r2.w * bf2f(h2[2]) + r3.w * bf2f(h3[2]);
        a3 += r0.w * bf2f(h0[3]) + r1.w * bf2f(h1[3]) + r2.w * bf2f(h2[3]) + r3.w * bf2f(h3[3]);
        a4 += r0.w * bf2f(h0[4]) + r1.w * bf2f(h1[4]) + r2.w * bf2f(h2[4]) + r3.w * bf2f(h3[4]);
        a5 += r0.w * bf2f(h0[5]) + r1.w * bf2f(h1[5]) + r2.w * bf2f(h2[5]) + r3.w * bf2f(h3[5]);
        a6 += r0.w * bf2f(h0[6]) + r1.w * bf2f(h1[6]) + r2.w * bf2f(h2[6]) + r3.w * bf2f(h3[6]);
        a7 += r0.w * bf2f(h0[7]) + r1.w * bf2f(h1[7]) + r2.w * bf2f(h2[7]) + r3.w * bf2f(h3[7]);
    }
    for (; j < e; ++j) {
        EdgeRec r = rec[j];
        ushort8v h = *(const ushort8v*)(yin + (((size_t)r.s) << 6) + q);
        a0 += r.w * bf2f(h[0]); a1 += r.w * bf2f(h[1]);
        a2 += r.w * bf2f(h[2]); a3 += r.w * bf2f(h[3]);
        a4 += r.w * bf2f(h[4]); a5 += r.w * bf2f(h[5]);
        a6 += r.w * bf2f(h[6]); a7 += r.w * bf2f(h[7]);
    }
    float dn = dinv[n];
    float dn2 = dn * dn;
    uint4 o;
    o.x = (unsigned)f2bf(dn2 * a0) | ((unsigned)f2bf(dn2 * a1) << 16);
    o.y = (unsigned)f2bf(dn2 * a2) | ((unsigned)f2bf(dn2 * a3) << 16);
    o.z = (unsigned)f2bf(dn2 * a4) | ((unsigned)f2bf(dn2 * a5) << 16);
    o.w = (unsigned)f2bf(dn2 * a6) | ((unsigned)f2bf(dn2 * a7) << 16);
    *(uint4*)(yout + (((size_t)n) << 6) + q) = o;
}

// last propagation fused with weighted layer-combine + row L2-normalize
// x_l = y_l * rdinv[n]; x3 = dinv[n] * sum ew y2[src]
__global__ void prop8_combine_kernel(const unsigned short* __restrict__ y2h,
                                     const float* __restrict__ x0,
                                     const unsigned short* __restrict__ y1h,
                                     const EdgeRec* __restrict__ rec,
                                     const int* __restrict__ start,
                                     const float* __restrict__ dinv,
                                     const float* __restrict__ rdinv,
                                     const float* __restrict__ lw,
                                     const int* __restrict__ perm,
                                     float* __restrict__ out) {
    int t = blockIdx.x * blockDim.x + threadIdx.x;
    int slot = t >> 3;
    int q = (t & 7) << 3;
    if (slot >= N_NODES) return;
    int n = perm[slot];
    int s = start[n], e = start[n + 1];
    float a0 = 0.f, a1 = 0.f, a2 = 0.f, a3 = 0.f;
    float a4 = 0.f, a5 = 0.f, a6 = 0.f, a7 = 0.f;
    int j = s;
    for (; j + 4 <= e; j += 4) {
        EdgeRec r0 = rec[j], r1 = rec[j + 1], r2 = rec[j + 2], r3 = rec[j + 3];
        ushort8v h0 = *(const ushort8v*)(y2h + (((size_t)r0.s) << 6) + q);
        ushort8v h1 = *(const ushort8v*)(y2h + (((size_t)r1.s) << 6) + q);
        ushort8v h2 = *(const ushort8v*)(y2h + (((size_t)r2.s) << 6) + q);
        ushort8v h3 = *(const ushort8v*)(y2h + (((size_t)r3.s) << 6) + q);
        a0 += r0.w * bf2f(h0[0]) + r1.w * bf2f(h1[0]) + r2.w * bf2f(h2[0]) + r3.w * bf2f(h3[0]);
        a1 += r0.w * bf2f(h0[1]) + r1.w * bf2f(h1[1]) + r2.w * bf2f(h2[1]) + r3.w * bf2f(h3[1]);
        a2 += r0.w * bf2f(h0[2]) + r1.w * bf2f(h1[2]) + r2.w * bf2f(h2[2]) + r3.w * bf2f(h3[2]);
        a3 += r0.w * bf2f(h0[3]) + r1.w * bf2f(h1[3]) + r2.w * bf2f(h2[3]) + r3.w * bf2f(h3[3]);
        a4 += r0.w * bf2f(h0[4]) + r1.w * bf2f(h1[4]) + r2.w * bf2f(h2[4]) + r3.w * bf2f(h3[4]);
        a5 += r0.w * bf2f(h0[5]) + r1.w * bf2f(h1[5]) + r2.w * bf2f(h2[5]) + r3.w * bf2f(h3[5]);
        a6 += r0.w * bf2f(h0[6]) + r1.w * bf2f(h1[6]) + r2.w * bf2f(h2[6]) + r3.w * bf2f(h3[6]);
        a7 += r0.w * bf2f(h0[7]) + r1.w * bf2f(h1[7]) + r2.w * bf2f(h2[7]) + r3.w * bf2f(h3[7]);
    }
    for (; j < e; ++j) {
        EdgeRec r = rec[j];
        ushort8v h = *(const ushort8v*)(y2h + (((size_t)r.s) << 6) + q);
        a0 += r.w * bf2f(h[0]); a1 += r.w * bf2f(h[1]);
        a2 += r.w * bf2f(h[2]); a3 += r.w * bf2f(h[3]);
        a4 += r.w * bf2f(h[4]); a5 += r.w * bf2f(h[5]);
        a6 += r.w * bf2f(h[6]); a7 += r.w * bf2f(h[7]);
    }
    float dn = dinv[n];
    float rn = rdinv[n];

    float w0 = lw[0], w1 = lw[1], w2 = lw[2], w3 = lw[3];
    float m = fmaxf(fmaxf(w0, w1), fmaxf(w2, w3));
    float e0 = expf(w0 - m), e1 = expf(w1 - m), e2 = expf(w2 - m), e3 = expf(w3 - m);
    float inv_s = 1.0f / (e0 + e1 + e2 + e3);
    float c1 = e1 * rn, c2 = e2 * rn, c3 = e3 * dn;

    size_t off = (((size_t)n) << 6) + q;
    float4 xa = *(const float4*)(x0 + off);
    float4 xb = *(const float4*)(x0 + off + 4);
    ushort8v h1v = *(const ushort8v*)(y1h + off);
    ushort8v h2v = *(const ushort8v*)(y2h + off);

    float v0 = (e0 * xa.x + c1 * bf2f(h1v[0]) + c2 * bf2f(h2v[0]) + c3 * a0) * inv_s;
    float v1 = (e0 * xa.y + c1 * bf2f(h1v[1]) + c2 * bf2f(h2v[1]) + c3 * a1) * inv_s;
    float v2 = (e0 * xa.z + c1 * bf2f(h1v[2]) + c2 * bf2f(h2v[2]) + c3 * a2) * inv_s;
    float v3 = (e0 * xa.w + c1 * bf2f(h1v[3]) + c2 * bf2f(h2v[3]) + c3 * a3) * inv_s;
    float v4 = (e0 * xb.x + c1 * bf2f(h1v[4]) + c2 * bf2f(h2v[4]) + c3 * a4) * inv_s;
    float v5 = (e0 * xb.y + c1 * bf2f(h1v[5]) + c2 * bf2f(h2v[5]) + c3 * a5) * inv_s;
    float v6 = (e0 * xb.z + c1 * bf2f(h1v[6]) + c2 * bf2f(h2v[6]) + c3 * a6) * inv_s;
    float v7 = (e0 * xb.w + c1 * bf2f(h1v[7]) + c2 * bf2f(h2v[7]) + c3 * a7) * inv_s;

    float sq = v0*v0 + v1*v1 + v2*v2 + v3*v3 + v4*v4 + v5*v5 + v6*v6 + v7*v7;
    #pragma unroll
    for (int o = 1; o < 8; o <<= 1) sq += __shfl_xor(sq, o, 64);  // within 8-lane group
    float nrm = fmaxf(sqrtf(sq), 1e-12f);
    float inv_n = 1.0f / nrm;

    float4 oa, ob;
    oa.x = v0 * inv_n; oa.y = v1 * inv_n; oa.z = v2 * inv_n; oa.w = v3 * inv_n;
    ob.x = v4 * inv_n; ob.y = v5 * inv_n; ob.z = v6 * inv_n; ob.w = v7 * inv_n;
    *(float4*)(out + off) = oa;
    *(float4*)(out + off + 4) = ob;
}

// ---------------------------------------------------------------------------
extern "C" void kernel_launch(void* const* d_in, const int* in_sizes, int n_in,
                              void* d_out, int out_size, void* d_ws, size_t ws_size,
                              hipStream_t stream) {
    const float* emb = (const float*)d_in[0];   // [N, 64]
    const float* lw  = (const float*)d_in[1];   // [4]
    const float* ew  = (const float*)d_in[2];   // [E]
    const int*   ei  = (const int*)d_in[3];     // [2, E]
    const int* row = ei;                        // sources
    const int* col = ei + N_EDGES;              // targets
    float* out = (float*)d_out;

    // workspace layout (8B-aligned pieces)
    char* p = (char*)d_ws;
    BinRec*  binned = (BinRec*)p;               p += (size_t)NBUCKET * CAP * sizeof(BinRec); // 12.8 MB
    EdgeRec* rec    = (EdgeRec*)p;              p += (size_t)N_EDGES * sizeof(EdgeRec);      // 9.6 MB
    unsigned short* y0h = (unsigned short*)p;   p += (size_t)N_NODES * EMB_DIM * 2;          // 12.8 MB
    unsigned short* y1h = (unsigned short*)p;   p += (size_t)N_NODES * EMB_DIM * 2;          // 12.8 MB
    unsigned short* y2h = (unsigned short*)p;   p += (size_t)N_NODES * EMB_DIM * 2;          // 12.8 MB
    float* dinv  = (float*)p;                   p += (size_t)N_NODES * 4;
    float* rdinv = (float*)p;                   p += (size_t)N_NODES * 4;
    int*   startA= (int*)p;                     p += (size_t)(N_NODES + 8) * 4;
    int*   perm  = (int*)p;                     p += (size_t)N_NODES * 4;
    int*   csr_base      = (int*)p;             p += (size_t)NBUCKET * 4;
    int*   bucket_cursor = (int*)p;             p += (size_t)NBUCKET * 4;
    int*   dhist   = (int*)p;                   p += (size_t)DBINS * 4;
    int*   dcursor = (int*)p;                   p += (size_t)DBINS * 4;

    const int B = 256;

    init_kernel<<<1, 1024, 0, stream>>>(bucket_cursor, dhist);
    bin_scatter<<<NBLK_BIN, 1024, 0, stream>>>(row, col, ew, bucket_cursor, binned);
    bucket_scan<<<1, 1024, 0, stream>>>(bucket_cursor, csr_base, startA);
    bucket_build<<<NBUCKET, B, 0, stream>>>(binned, bucket_cursor, csr_base, emb,
                                            dinv, rdinv, startA, rec, y0h, dhist);
    deg_scan<<<1, DBINS, 0, stream>>>(dhist, dcursor);
    deg_scatter<<<NBLK_DEG, B, 0, stream>>>(startA, dcursor, perm);

    long pt = (long)N_NODES * 8;    // 8 lanes per node
    int pgrid = (int)((pt + B - 1) / B);
    prop8_kernel<<<pgrid, B, 0, stream>>>(y0h, y1h, rec, startA, dinv, perm);
    prop8_kernel<<<pgrid, B, 0, stream>>>(y1h, y2h, rec, startA, dinv, perm);
    prop8_combine_kernel<<<pgrid, B, 0, stream>>>(y2h, emb, y1h, rec, startA, dinv,
                                                  rdinv, lw, perm, out);
}

// Round 10
// 150.833 us; speedup vs baseline: 5.9962x; 1.0415x over previous
//
#include <hip/hip_runtime.h>

#define N_NODES 100000
#define EMB_DIM 64
#define N_EDGES 1200000

#define BSHIFT  7
#define BNODES  128
#define NBUCKET ((N_NODES + BNODES - 1) / BNODES)   // 782
#define CAP     2048                                 // padded bucket capacity
#define EPB     4096                                 // edges per binning block
#define NBLK_BIN ((N_EDGES + EPB - 1) / EPB)         // 293

#define DBINS 512
#define DNPB  1024
#define NBLK_DEG ((N_NODES + DNPB - 1) / DNPB)       // 98

#define WSCALE 32767.0f
#define WINV   (1.0f / 32767.0f)

typedef unsigned short ushort8v __attribute__((ext_vector_type(8)));

struct __align__(8) BinRec {
    unsigned meta;  // src (bits 0..19) | local_dst (bits 20..26)
    float    ew;
};

// bf16 helpers (RNE)
__device__ __forceinline__ unsigned short f2bf(float f) {
    unsigned u = __float_as_uint(f);
    u += 0x7FFFu + ((u >> 16) & 1u);
    return (unsigned short)(u >> 16);
}
__device__ __forceinline__ float bf2f(unsigned short h) {
    return __uint_as_float((unsigned)h << 16);
}

// ---------------------------------------------------------------------------
__global__ void init_kernel(int* __restrict__ bucket_cursor, int* __restrict__ dhist) {
    int t = threadIdx.x;   // 1024
    if (t < NBUCKET) bucket_cursor[t] = t * CAP;
    if (t < DBINS)   dhist[t] = 0;
}

// One-pass binning into padded per-bucket windows (direct reservation).
__global__ void bin_scatter(const int* __restrict__ row,
                            const int* __restrict__ col,
                            const float* __restrict__ ew,
                            int* __restrict__ bucket_cursor,
                            BinRec* __restrict__ binned) {
    __shared__ int hcnt[NBUCKET];
    __shared__ int hbase[NBUCKET];
    int tid = threadIdx.x;   // 1024
    if (tid < NBUCKET) hcnt[tid] = 0;
    __syncthreads();
    int base = blockIdx.x * EPB;
    int end = base + EPB; if (end > N_EDGES) end = N_EDGES;
    for (int e = base + tid; e < end; e += 1024)
        atomicAdd(&hcnt[col[e] >> BSHIFT], 1);
    __syncthreads();
    if (tid < NBUCKET) {
        int c = hcnt[tid];
        hbase[tid] = c ? atomicAdd(&bucket_cursor[tid], c) : 0;
        hcnt[tid] = 0;   // reuse as local cursor
    }
    __syncthreads();
    for (int e = base + tid; e < end; e += 1024) {
        int c = col[e];
        int b = c >> BSHIFT;
        int rk = atomicAdd(&hcnt[b], 1);
        BinRec r;
        r.meta = (unsigned)row[e] | ((unsigned)(c & (BNODES - 1)) << 20);
        r.ew = ew[e];
        binned[hbase[b] + rk] = r;
    }
}

// Exclusive scan of bucket counts (derived from cursors) -> CSR bases
__global__ void bucket_scan(const int* __restrict__ cursor,
                            int* __restrict__ csr_base,
                            int* __restrict__ start) {
    __shared__ int ws[16];
    int t = threadIdx.x;            // 1024 threads
    int lane = t & 63, wid = t >> 6;
    int v = (t < NBUCKET) ? (cursor[t] - t * CAP) : 0;
    int inc = v;
    #pragma unroll
    for (int o = 1; o < 64; o <<= 1) {
        int u = __shfl_up(inc, o, 64);
        if (lane >= o) inc += u;
    }
    if (lane == 63) ws[wid] = inc;
    __syncthreads();
    int woff = 0;
    for (int w = 0; w < wid; ++w) woff += ws[w];
    if (t < NBUCKET) csr_base[t] = woff + inc - v;
    if (t == 0) start[N_NODES] = N_EDGES;
}

// Merged stats+scatter+cvt: per-bucket node counts/deg (LDS), local scan ->
// start[], dinv[], rdinv[]; scatter packed {src,wq} into CSR rec[]; convert
// this bucket's emb rows -> y0 bf16 scaled by dinv; LDS deg histogram.
__global__ void bucket_build(const BinRec* __restrict__ binned,
                             const int* __restrict__ cursor,
                             const int* __restrict__ csr_base,
                             const float* __restrict__ emb,
                             float* __restrict__ dinv,
                             float* __restrict__ rdinv,
                             int* __restrict__ start,
                             unsigned* __restrict__ rec,
                             unsigned short* __restrict__ y0,
                             int* __restrict__ dhist) {
    __shared__ int   cnt[BNODES];
    __shared__ float deg[BNODES];
    __shared__ int   cur[BNODES];
    __shared__ int   dh[DBINS];
    __shared__ int   wsum[2];
    int b = blockIdx.x;
    int tid = threadIdx.x;   // 256
    if (tid < BNODES) { cnt[tid] = 0; deg[tid] = 0.0f; }
    for (int i = tid; i < DBINS; i += 256) dh[i] = 0;
    __syncthreads();
    int s = b * CAP;
    int n = cursor[b] - s;
    for (int i = tid; i < n; i += 256) {
        BinRec r = binned[s + i];
        int l = r.meta >> 20;
        atomicAdd(&cnt[l], 1);
        atomicAdd(&deg[l], r.ew);
    }
    __syncthreads();
    int lane = tid & 63, wid = tid >> 6;
    int v = (tid < BNODES) ? cnt[tid] : 0;
    int inc = v;
    #pragma unroll
    for (int o = 1; o < 64; o <<= 1) {
        int u = __shfl_up(inc, o, 64);
        if (lane >= o) inc += u;
    }
    if (tid < BNODES && lane == 63) wsum[wid] = inc;
    __syncthreads();
    if (tid < BNODES) {
        int excl = inc - v + ((wid == 1) ? wsum[0] : 0);
        int node = (b << BSHIFT) + tid;
        if (node < N_NODES) {
            int st = csr_base[b] + excl;
            start[node] = st;
            cur[tid] = st;
            float d = deg[tid];
            dinv[node]  = (d > 0.0f) ? rsqrtf(d) : 0.0f;
            rdinv[node] = (d > 0.0f) ? sqrtf(d)  : 0.0f;
            int dd = v; if (dd > DBINS - 1) dd = DBINS - 1;
            atomicAdd(&dh[dd], 1);
        } else {
            cur[tid] = 0;
        }
    }
    __syncthreads();
    // scatter into CSR (packed 4B: src<<15 | wq)
    for (int i = tid; i < n; i += 256) {
        BinRec r = binned[s + i];
        int l = r.meta >> 20;
        int pos = atomicAdd(&cur[l], 1);
        unsigned wq = (unsigned)rintf(r.ew * WSCALE);
        rec[pos] = ((r.meta & 0xFFFFFu) << 15) | wq;
    }
    // flush degree histogram
    for (int i = tid; i < DBINS; i += 256)
        if (dh[i]) atomicAdd(&dhist[i], dh[i]);
    // convert bucket's emb rows -> y0 (bf16, scaled by dinv)
    #pragma unroll
    for (int pass = 0; pass < 4; ++pass) {
        int g = (pass * 256 + tid) * 8;    // elem index within bucket [0, 8192)
        int l = g >> 6;
        int node = (b << BSHIFT) + l;
        if (node < N_NODES) {
            float d = deg[l];
            float dn = (d > 0.0f) ? rsqrtf(d) : 0.0f;
            size_t off = (((size_t)node) << 6) + (g & 63);
            float4 a = *(const float4*)(emb + off);
            float4 bb = *(const float4*)(emb + off + 4);
            uint4 o;
            o.x = (unsigned)f2bf(dn * a.x)  | ((unsigned)f2bf(dn * a.y)  << 16);
            o.y = (unsigned)f2bf(dn * a.z)  | ((unsigned)f2bf(dn * a.w)  << 16);
            o.z = (unsigned)f2bf(dn * bb.x) | ((unsigned)f2bf(dn * bb.y) << 16);
            o.w = (unsigned)f2bf(dn * bb.z) | ((unsigned)f2bf(dn * bb.w) << 16);
            *(uint4*)(y0 + off) = o;
        }
    }
}

// ---------------------------------------------------------------------------
__global__ void deg_scan(const int* __restrict__ dhist, int* __restrict__ dcursor) {
    __shared__ int ws[8];
    int t = threadIdx.x;            // 512 threads
    int lane = t & 63, wid = t >> 6;
    int v = dhist[t];
    int inc = v;
    #pragma unroll
    for (int o = 1; o < 64; o <<= 1) {
        int u = __shfl_up(inc, o, 64);
        if (lane >= o) inc += u;
    }
    if (lane == 63) ws[wid] = inc;
    __syncthreads();
    int woff = 0;
    for (int w = 0; w < wid; ++w) woff += ws[w];
    dcursor[t] = woff + inc - v;   // exclusive
}

__global__ void deg_scatter(const int* __restrict__ start,
                            int* __restrict__ dcursor,
                            int* __restrict__ perm) {
    __shared__ int h[DBINS];
    __shared__ int hb[DBINS];
    int tid = threadIdx.x;
    for (int i = tid; i < DBINS; i += 256) h[i] = 0;
    __syncthreads();
    int base = blockIdx.x * DNPB;
    int end = base + DNPB; if (end > N_NODES) end = N_NODES;
    for (int n = base + tid; n < end; n += 256) {
        int d = start[n + 1] - start[n];
        if (d > DBINS - 1) d = DBINS - 1;
        atomicAdd(&h[d], 1);
    }
    __syncthreads();
    for (int i = tid; i < DBINS; i += 256) {
        int c = h[i];
        hb[i] = c ? atomicAdd(&dcursor[i], c) : 0;
        h[i] = 0;   // reuse as local cursor
    }
    __syncthreads();
    for (int n = base + tid; n < end; n += 256) {
        int d = start[n + 1] - start[n];
        if (d > DBINS - 1) d = DBINS - 1;
        int rk = atomicAdd(&h[d], 1);
        perm[hb[d] + rk] = n;
    }
}

// ---------------------------------------------------------------------------
#define DECODE(v, src, w)  { src = (int)((v) >> 15); w = (float)((v) & 0x7FFFu) * WINV; }

#define GATHER_ACC(vv)                                                          \
    {   int _s; float _w; DECODE(vv, _s, _w);                                   \
        ushort8v _h = *(const ushort8v*)(yin + (((size_t)_s) << 6) + q);        \
        a0 += _w * bf2f(_h[0]); a1 += _w * bf2f(_h[1]);                         \
        a2 += _w * bf2f(_h[2]); a3 += _w * bf2f(_h[3]);                         \
        a4 += _w * bf2f(_h[4]); a5 += _w * bf2f(_h[5]);                         \
        a6 += _w * bf2f(_h[6]); a7 += _w * bf2f(_h[7]); }

// 8 lanes per node, 8 dims per lane; 8/4/1 unrolled gather loop.
__global__ void prop8_kernel(const unsigned short* __restrict__ yin,
                             unsigned short* __restrict__ yout,
                             const unsigned* __restrict__ rec,
                             const int* __restrict__ start,
                             const float* __restrict__ dinv,
                             const int* __restrict__ perm) {
    int t = blockIdx.x * blockDim.x + threadIdx.x;
    int slot = t >> 3;
    int q = (t & 7) << 3;          // dim offset, 8 dims per lane
    if (slot >= N_NODES) return;
    int n = perm[slot];
    int s = start[n], e = start[n + 1];
    float a0 = 0.f, a1 = 0.f, a2 = 0.f, a3 = 0.f;
    float a4 = 0.f, a5 = 0.f, a6 = 0.f, a7 = 0.f;
    int j = s;
    for (; j + 8 <= e; j += 8) {
        unsigned v0 = rec[j],     v1 = rec[j + 1], v2 = rec[j + 2], v3 = rec[j + 3];
        unsigned v4 = rec[j + 4], v5 = rec[j + 5], v6 = rec[j + 6], v7 = rec[j + 7];
        const ushort8v* p0 = (const ushort8v*)(yin + (((size_t)(v0 >> 15)) << 6) + q);
        const ushort8v* p1 = (const ushort8v*)(yin + (((size_t)(v1 >> 15)) << 6) + q);
        const ushort8v* p2 = (const ushort8v*)(yin + (((size_t)(v2 >> 15)) << 6) + q);
        const ushort8v* p3 = (const ushort8v*)(yin + (((size_t)(v3 >> 15)) << 6) + q);
        const ushort8v* p4 = (const ushort8v*)(yin + (((size_t)(v4 >> 15)) << 6) + q);
        const ushort8v* p5 = (const ushort8v*)(yin + (((size_t)(v5 >> 15)) << 6) + q);
        const ushort8v* p6 = (const ushort8v*)(yin + (((size_t)(v6 >> 15)) << 6) + q);
        const ushort8v* p7 = (const ushort8v*)(yin + (((size_t)(v7 >> 15)) << 6) + q);
        ushort8v h0 = *p0, h1 = *p1, h2 = *p2, h3 = *p3;
        ushort8v h4 = *p4, h5 = *p5, h6 = *p6, h7 = *p7;
        float w0 = (float)(v0 & 0x7FFFu) * WINV, w1 = (float)(v1 & 0x7FFFu) * WINV;
        float w2 = (float)(v2 & 0x7FFFu) * WINV, w3 = (float)(v3 & 0x7FFFu) * WINV;
        float w4 = (float)(v4 & 0x7FFFu) * WINV, w5 = (float)(v5 & 0x7FFFu) * WINV;
        float w6 = (float)(v6 & 0x7FFFu) * WINV, w7 = (float)(v7 & 0x7FFFu) * WINV;
        a0 += w0*bf2f(h0[0]) + w1*bf2f(h1[0]) + w2*bf2f(h2[0]) + w3*bf2f(h3[0])
            + w4*bf2f(h4[0]) + w5*bf2f(h5[0]) + w6*bf2f(h6[0]) + w7*bf2f(h7[0]);
        a1 += w0*bf2f(h0[1]) + w1*bf2f(h1[1]) + w2*bf2f(h2[1]) + w3*bf2f(h3[1])
            + w4*bf2f(h4[1]) + w5*bf2f(h5[1]) + w6*bf2f(h6[1]) + w7*bf2f(h7[1]);
        a2 += w0*bf2f(h0[2]) + w1*bf2f(h1[2]) + w2*bf2f(h2[2]) + w3*bf2f(h3[2])
            + w4*bf2f(h4[2]) + w5*bf2f(h5[2]) + w6*bf2f(h6[2]) + w7*bf2f(h7[2]);
        a3 += w0*bf2f(h0[3]) + w1*bf2f(h1[3]) + w2*bf2f(h2[3]) + w3*bf2f(h3[3])
            + w4*bf2f(h4[3]) + w5*bf2f(h5[3]) + w6*bf2f(h6[3]) + w7*bf2f(h7[3]);
        a4 += w0*bf2f(h0[4]) + w1*bf2f(h1[4]) + w2*bf2f(h2[4]) + w3*bf2f(h3[4])
            + w4*bf2f(h4[4]) + w5*bf2f(h5[4]) + w6*bf2f(h6[4]) + w7*bf2f(h7[4]);
        a5 += w0*bf2f(h0[5]) + w1*bf2f(h1[5]) + w2*bf2f(h2[5]) + w3*bf2f(h3[5])
            + w4*bf2f(h4[5]) + w5*bf2f(h5[5]) + w6*bf2f(h6[5]) + w7*bf2f(h7[5]);
        a6 += w0*bf2f(h0[6]) + w1*bf2f(h1[6]) + w2*bf2f(h2[6]) + w3*bf2f(h3[6])
            + w4*bf2f(h4[6]) + w5*bf2f(h5[6]) + w6*bf2f(h6[6]) + w7*bf2f(h7[6]);
        a7 += w0*bf2f(h0[7]) + w1*bf2f(h1[7]) + w2*bf2f(h2[7]) + w3*bf2f(h3[7])
            + w4*bf2f(h4[7]) + w5*bf2f(h5[7]) + w6*bf2f(h6[7]) + w7*bf2f(h7[7]);
    }
    if (j + 4 <= e) {
        unsigned v0 = rec[j], v1 = rec[j + 1], v2 = rec[j + 2], v3 = rec[j + 3];
        ushort8v h0 = *(const ushort8v*)(yin + (((size_t)(v0 >> 15)) << 6) + q);
        ushort8v h1 = *(const ushort8v*)(yin + (((size_t)(v1 >> 15)) << 6) + q);
        ushort8v h2 = *(const ushort8v*)(yin + (((size_t)(v2 >> 15)) << 6) + q);
        ushort8v h3 = *(const ushort8v*)(yin + (((size_t)(v3 >> 15)) << 6) + q);
        float w0 = (float)(v0 & 0x7FFFu) * WINV, w1 = (float)(v1 & 0x7FFFu) * WINV;
        float w2 = (float)(v2 & 0x7FFFu) * WINV, w3 = (float)(v3 & 0x7FFFu) * WINV;
        a0 += w0*bf2f(h0[0]) + w1*bf2f(h1[0]) + w2*bf2f(h2[0]) + w3*bf2f(h3[0]);
        a1 += w0*bf2f(h0[1]) + w1*bf2f(h1[1]) + w2*bf2f(h2[1]) + w3*bf2f(h3[1]);
        a2 += w0*bf2f(h0[2]) + w1*bf2f(h1[2]) + w2*bf2f(h2[2]) + w3*bf2f(h3[2]);
        a3 += w0*bf2f(h0[3]) + w1*bf2f(h1[3]) + w2*bf2f(h2[3]) + w3*bf2f(h3[3]);
        a4 += w0*bf2f(h0[4]) + w1*bf2f(h1[4]) + w2*bf2f(h2[4]) + w3*bf2f(h3[4]);
        a5 += w0*bf2f(h0[5]) + w1*bf2f(h1[5]) + w2*bf2f(h2[5]) + w3*bf2f(h3[5]);
        a6 += w0*bf2f(h0[6]) + w1*bf2f(h1[6]) + w2*bf2f(h2[6]) + w3*bf2f(h3[6]);
        a7 += w0*bf2f(h0[7]) + w1*bf2f(h1[7]) + w2*bf2f(h2[7]) + w3*bf2f(h3[7]);
        j += 4;
    }
    for (; j < e; ++j) GATHER_ACC(rec[j]);
    float dn = dinv[n];
    float dn2 = dn * dn;
    uint4 o;
    o.x = (unsigned)f2bf(dn2 * a0) | ((unsigned)f2bf(dn2 * a1) << 16);
    o.y = (unsigned)f2bf(dn2 * a2) | ((unsigned)f2bf(dn2 * a3) << 16);
    o.z = (unsigned)f2bf(dn2 * a4) | ((unsigned)f2bf(dn2 * a5) << 16);
    o.w = (unsigned)f2bf(dn2 * a6) | ((unsigned)f2bf(dn2 * a7) << 16);
    *(uint4*)(yout + (((size_t)n) << 6) + q) = o;
}

// last propagation fused with layer-combine + row L2-normalize.
// x_l = y_l*rdinv; x3 = dinv * sum ew y2[src]; x0 via y0h (emb fallback deg==0)
__global__ void prop8_combine_kernel(const unsigned short* __restrict__ yin,  // y2h
                                     const unsigned short* __restrict__ y0h,
                                     const unsigned short* __restrict__ y1h,
                                     const float* __restrict__ emb,
                                     const unsigned* __restrict__ rec,
                                     const int* __restrict__ start,
                                     const float* __restrict__ dinv,
                                     const float* __restrict__ rdinv,
                                     const float* __restrict__ lw,
                                     const int* __restrict__ perm,
                                     float* __restrict__ out) {
    int t = blockIdx.x * blockDim.x + threadIdx.x;
    int slot = t >> 3;
    int q = (t & 7) << 3;
    if (slot >= N_NODES) return;
    int n = perm[slot];
    int s = start[n], e = start[n + 1];
    float a0 = 0.f, a1 = 0.f, a2 = 0.f, a3 = 0.f;
    float a4 = 0.f, a5 = 0.f, a6 = 0.f, a7 = 0.f;
    int j = s;
    for (; j + 8 <= e; j += 8) {
        unsigned v0 = rec[j],     v1 = rec[j + 1], v2 = rec[j + 2], v3 = rec[j + 3];
        unsigned v4 = rec[j + 4], v5 = rec[j + 5], v6 = rec[j + 6], v7 = rec[j + 7];
        ushort8v h0 = *(const ushort8v*)(yin + (((size_t)(v0 >> 15)) << 6) + q);
        ushort8v h1 = *(const ushort8v*)(yin + (((size_t)(v1 >> 15)) << 6) + q);
        ushort8v h2 = *(const ushort8v*)(yin + (((size_t)(v2 >> 15)) << 6) + q);
        ushort8v h3 = *(const ushort8v*)(yin + (((size_t)(v3 >> 15)) << 6) + q);
        ushort8v h4 = *(const ushort8v*)(yin + (((size_t)(v4 >> 15)) << 6) + q);
        ushort8v h5 = *(const ushort8v*)(yin + (((size_t)(v5 >> 15)) << 6) + q);
        ushort8v h6 = *(const ushort8v*)(yin + (((size_t)(v6 >> 15)) << 6) + q);
        ushort8v h7 = *(const ushort8v*)(yin + (((size_t)(v7 >> 15)) << 6) + q);
        float w0 = (float)(v0 & 0x7FFFu) * WINV, w1 = (float)(v1 & 0x7FFFu) * WINV;
        float w2 = (float)(v2 & 0x7FFFu) * WINV, w3 = (float)(v3 & 0x7FFFu) * WINV;
        float w4 = (float)(v4 & 0x7FFFu) * WINV, w5 = (float)(v5 & 0x7FFFu) * WINV;
        float w6 = (float)(v6 & 0x7FFFu) * WINV, w7 = (float)(v7 & 0x7FFFu) * WINV;
        a0 += w0*bf2f(h0[0]) + w1*bf2f(h1[0]) + w2*bf2f(h2[0]) + w3*bf2f(h3[0])
            + w4*bf2f(h4[0]) + w5*bf2f(h5[0]) + w6*bf2f(h6[0]) + w7*bf2f(h7[0]);
        a1 += w0*bf2f(h0[1]) + w1*bf2f(h1[1]) + w2*bf2f(h2[1]) + w3*bf2f(h3[1])
            + w4*bf2f(h4[1]) + w5*bf2f(h5[1]) + w6*bf2f(h6[1]) + w7*bf2f(h7[1]);
        a2 += w0*bf2f(h0[2]) + w1*bf2f(h1[2]) + w2*bf2f(h2[2]) + w3*bf2f(h3[2])
            + w4*bf2f(h4[2]) + w5*bf2f(h5[2]) + w6*bf2f(h6[2]) + w7*bf2f(h7[2]);
        a3 += w0*bf2f(h0[3]) + w1*bf2f(h1[3]) + w2*bf2f(h2[3]) + w3*bf2f(h3[3])
            + w4*bf2f(h4[3]) + w5*bf2f(h5[3]) + w6*bf2f(h6[3]) + w7*bf2f(h7[3]);
        a4 += w0*bf2f(h0[4]) + w1*bf2f(h1[4]) + w2*bf2f(h2[4]) + w3*bf2f(h3[4])
            + w4*bf2f(h4[4]) + w5*bf2f(h5[4]) + w6*bf2f(h6[4]) + w7*bf2f(h7[4]);
        a5 += w0*bf2f(h0[5]) + w1*bf2f(h1[5]) + w2*bf2f(h2[5]) + w3*bf2f(h3[5])
            + w4*bf2f(h4[5]) + w5*bf2f(h5[5]) + w6*bf2f(h6[5]) + w7*bf2f(h7[5]);
        a6 += w0*bf2f(h0[6]) + w1*bf2f(h1[6]) + w2*bf2f(h2[6]) + w3*bf2f(h3[6])
            + w4*bf2f(h4[6]) + w5*bf2f(h5[6]) + w6*bf2f(h6[6]) + w7*bf2f(h7[6]);
        a7 += w0*bf2f(h0[7]) + w1*bf2f(h1[7]) + w2*bf2f(h2[7]) + w3*bf2f(h3[7])
            + w4*bf2f(h4[7]) + w5*bf2f(h5[7]) + w6*bf2f(h6[7]) + w7*bf2f(h7[7]);
    }
    if (j + 4 <= e) {
        unsigned v0 = rec[j], v1 = rec[j + 1], v2 = rec[j + 2], v3 = rec[j + 3];
        ushort8v h0 = *(const ushort8v*)(yin + (((size_t)(v0 >> 15)) << 6) + q);
        ushort8v h1 = *(const ushort8v*)(yin + (((size_t)(v1 >> 15)) << 6) + q);
        ushort8v h2 = *(const ushort8v*)(yin + (((size_t)(v2 >> 15)) << 6) + q);
        ushort8v h3 = *(const ushort8v*)(yin + (((size_t)(v3 >> 15)) << 6) + q);
        float w0 = (float)(v0 & 0x7FFFu) * WINV, w1 = (float)(v1 & 0x7FFFu) * WINV;
        float w2 = (float)(v2 & 0x7FFFu) * WINV, w3 = (float)(v3 & 0x7FFFu) * WINV;
        a0 += w0*bf2f(h0[0]) + w1*bf2f(h1[0]) + w2*bf2f(h2[0]) + w3*bf2f(h3[0]);
        a1 += w0*bf2f(h0[1]) + w1*bf2f(h1[1]) + w2*bf2f(h2[1]) + w3*bf2f(h3[1]);
        a2 += w0*bf2f(h0[2]) + w1*bf2f(h1[2]) + w2*bf2f(h2[2]) + w3*bf2f(h3[2]);
        a3 += w0*bf2f(h0[3]) + w1*bf2f(h1[3]) + w2*bf2f(h2[3]) + w3*bf2f(h3[3]);
        a4 += w0*bf2f(h0[4]) + w1*bf2f(h1[4]) + w2*bf2f(h2[4]) + w3*bf2f(h3[4]);
        a5 += w0*bf2f(h0[5]) + w1*bf2f(h1[5]) + w2*bf2f(h2[5]) + w3*bf2f(h3[5]);
        a6 += w0*bf2f(h0[6]) + w1*bf2f(h1[6]) + w2*bf2f(h2[6]) + w3*bf2f(h3[6]);
        a7 += w0*bf2f(h0[7]) + w1*bf2f(h1[7]) + w2*bf2f(h2[7]) + w3*bf2f(h3[7]);
        j += 4;
    }
    { const unsigned short* yin_ = yin;
      for (; j < e; ++j) { const unsigned short* yin2 = yin_;
        unsigned vv = rec[j];
        int _s = (int)(vv >> 15); float _w = (float)(vv & 0x7FFFu) * WINV;
        ushort8v _h = *(const ushort8v*)(yin2 + (((size_t)_s) << 6) + q);
        a0 += _w * bf2f(_h[0]); a1 += _w * bf2f(_h[1]);
        a2 += _w * bf2f(_h[2]); a3 += _w * bf2f(_h[3]);
        a4 += _w * bf2f(_h[4]); a5 += _w * bf2f(_h[5]);
        a6 += _w * bf2f(_h[6]); a7 += _w * bf2f(_h[7]); } }

    float dn = dinv[n];
    float rn = rdinv[n];

    float w0 = lw[0], w1 = lw[1], w2 = lw[2], w3 = lw[3];
    float m = fmaxf(fmaxf(w0, w1), fmaxf(w2, w3));
    float e0 = expf(w0 - m), e1 = expf(w1 - m), e2 = expf(w2 - m), e3 = expf(w3 - m);
    float inv_s = 1.0f / (e0 + e1 + e2 + e3);
    float c0 = e0 * rn, c1 = e1 * rn, c2 = e2 * rn, c3 = e3 * dn;

    size_t off = (((size_t)n) << 6) + q;
    float v0, v1, v2, v3, v4, v5, v6, v7;
    if (rn != 0.0f) {
        ushort8v h0v = *(const ushort8v*)(y0h + off);
        ushort8v h1v = *(const ushort8v*)(y1h + off);
        ushort8v h2v = *(const ushort8v*)(yin + off);
        v0 = (c0 * bf2f(h0v[0]) + c1 * bf2f(h1v[0]) + c2 * bf2f(h2v[0]) + c3 * a0) * inv_s;
        v1 = (c0 * bf2f(h0v[1]) + c1 * bf2f(h1v[1]) + c2 * bf2f(h2v[1]) + c3 * a1) * inv_s;
        v2 = (c0 * bf2f(h0v[2]) + c1 * bf2f(h1v[2]) + c2 * bf2f(h2v[2]) + c3 * a2) * inv_s;
        v3 = (c0 * bf2f(h0v[3]) + c1 * bf2f(h1v[3]) + c2 * bf2f(h2v[3]) + c3 * a3) * inv_s;
        v4 = (c0 * bf2f(h0v[4]) + c1 * bf2f(h1v[4]) + c2 * bf2f(h2v[4]) + c3 * a4) * inv_s;
        v5 = (c0 * bf2f(h0v[5]) + c1 * bf2f(h1v[5]) + c2 * bf2f(h2v[5]) + c3 * a5) * inv_s;
        v6 = (c0 * bf2f(h0v[6]) + c1 * bf2f(h1v[6]) + c2 * bf2f(h2v[6]) + c3 * a6) * inv_s;
        v7 = (c0 * bf2f(h0v[7]) + c1 * bf2f(h1v[7]) + c2 * bf2f(h2v[7]) + c3 * a7) * inv_s;
    } else {
        // isolated node: x0 = emb, x1..x3 = 0
        float4 xa = *(const float4*)(emb + off);
        float4 xb = *(const float4*)(emb + off + 4);
        float c = e0 * inv_s;
        v0 = c * xa.x; v1 = c * xa.y; v2 = c * xa.z; v3 = c * xa.w;
        v4 = c * xb.x; v5 = c * xb.y; v6 = c * xb.z; v7 = c * xb.w;
    }

    float sq = v0*v0 + v1*v1 + v2*v2 + v3*v3 + v4*v4 + v5*v5 + v6*v6 + v7*v7;
    #pragma unroll
    for (int o = 1; o < 8; o <<= 1) sq += __shfl_xor(sq, o, 64);  // within 8-lane group
    float nrm = fmaxf(sqrtf(sq), 1e-12f);
    float inv_n = 1.0f / nrm;

    float4 oa, ob;
    oa.x = v0 * inv_n; oa.y = v1 * inv_n; oa.z = v2 * inv_n; oa.w = v3 * inv_n;
    ob.x = v4 * inv_n; ob.y = v5 * inv_n; ob.z = v6 * inv_n; ob.w = v7 * inv_n;
    *(float4*)(out + off) = oa;
    *(float4*)(out + off + 4) = ob;
}

// ---------------------------------------------------------------------------
extern "C" void kernel_launch(void* const* d_in, const int* in_sizes, int n_in,
                              void* d_out, int out_size, void* d_ws, size_t ws_size,
                              hipStream_t stream) {
    const float* emb = (const float*)d_in[0];   // [N, 64]
    const float* lw  = (const float*)d_in[1];   // [4]
    const float* ew  = (const float*)d_in[2];   // [E]
    const int*   ei  = (const int*)d_in[3];     // [2, E]
    const int* row = ei;                        // sources
    const int* col = ei + N_EDGES;              // targets
    float* out = (float*)d_out;

    // workspace layout (8B-aligned pieces)
    char* p = (char*)d_ws;
    BinRec*  binned = (BinRec*)p;               p += (size_t)NBUCKET * CAP * sizeof(BinRec); // 12.8 MB
    unsigned* rec   = (unsigned*)p;             p += (size_t)N_EDGES * 4;                    // 4.8 MB
    unsigned short* y0h = (unsigned short*)p;   p += (size_t)N_NODES * EMB_DIM * 2;          // 12.8 MB
    unsigned short* y1h = (unsigned short*)p;   p += (size_t)N_NODES * EMB_DIM * 2;          // 12.8 MB
    unsigned short* y2h = (unsigned short*)p;   p += (size_t)N_NODES * EMB_DIM * 2;          // 12.8 MB
    float* dinv  = (float*)p;                   p += (size_t)N_NODES * 4;
    float* rdinv = (float*)p;                   p += (size_t)N_NODES * 4;
    int*   startA= (int*)p;                     p += (size_t)(N_NODES + 8) * 4;
    int*   perm  = (int*)p;                     p += (size_t)N_NODES * 4;
    int*   csr_base      = (int*)p;             p += (size_t)NBUCKET * 4;
    int*   bucket_cursor = (int*)p;             p += (size_t)NBUCKET * 4;
    int*   dhist   = (int*)p;                   p += (size_t)DBINS * 4;
    int*   dcursor = (int*)p;                   p += (size_t)DBINS * 4;

    const int B = 256;

    init_kernel<<<1, 1024, 0, stream>>>(bucket_cursor, dhist);
    bin_scatter<<<NBLK_BIN, 1024, 0, stream>>>(row, col, ew, bucket_cursor, binned);
    bucket_scan<<<1, 1024, 0, stream>>>(bucket_cursor, csr_base, startA);
    bucket_build<<<NBUCKET, B, 0, stream>>>(binned, bucket_cursor, csr_base, emb,
                                            dinv, rdinv, startA, rec, y0h, dhist);
    deg_scan<<<1, DBINS, 0, stream>>>(dhist, dcursor);
    deg_scatter<<<NBLK_DEG, B, 0, stream>>>(startA, dcursor, perm);

    long pt = (long)N_NODES * 8;    // 8 lanes per node
    int pgrid = (int)((pt + B - 1) / B);
    prop8_kernel<<<pgrid, B, 0, stream>>>(y0h, y1h, rec, startA, dinv, perm);
    prop8_kernel<<<pgrid, B, 0, stream>>>(y1h, y2h, rec, startA, dinv, perm);
    prop8_combine_kernel<<<pgrid, B, 0, stream>>>(y2h, y0h, y1h, emb, rec, startA,
                                                  dinv, rdinv, lw, perm, out);
}